// Round 3
// baseline (1070.665 us; speedup 1.0000x reference)
//
#include <hip/hip_runtime.h>
#include <hip/hip_bf16.h>
#include <math.h>

// Problem constants (from reference)
#define B_   8
#define E_   256
#define N_   32
#define D_   512
#define RD_  768
#define R_   2000
#define L_   2
#define K_   8
#define M_   32
#define H_   8
#define DH_  64
#define HL_  4096

__device__ __forceinline__ float gelu_exact(float x) {
    return 0.5f * x * (1.0f + erff(x * 0.70710678118654752f));
}

// ---------------------------------------------------------------------------
// C[M,N] = A[M,K] @ B[N,K]^T + bias (all fp32), optional exact-GELU.
// 64x64 tile, BK=16, 256 threads, 4x4 per-thread microtile.
// Requires N % 64 == 0, K % 16 == 0 (holds at every call site).
// ---------------------------------------------------------------------------
template <int ACT_GELU>
__global__ void gemm_nt(const float* __restrict__ A, const float* __restrict__ Bm,
                        const float* __restrict__ bias, float* __restrict__ C,
                        int M, int N, int K) {
    __shared__ float As[16][65];
    __shared__ float Bs[16][65];
    const int tid = threadIdx.x;
    const int bm = blockIdx.y * 64, bn = blockIdx.x * 64;
    const int tx = tid & 15, ty = tid >> 4;
    const int lrow = tid >> 2;            // 0..63
    const int lk = (tid & 3) << 2;        // 0,4,8,12

    float acc[4][4] = {{0.f}};
    const int arow = bm + lrow;
    const int brow = bn + lrow;

    for (int k0 = 0; k0 < K; k0 += 16) {
        float4 a4 = make_float4(0.f, 0.f, 0.f, 0.f);
        if (arow < M) a4 = *(const float4*)(A + (size_t)arow * K + k0 + lk);
        float4 b4 = *(const float4*)(Bm + (size_t)brow * K + k0 + lk);
        __syncthreads();
        As[lk + 0][lrow] = a4.x; As[lk + 1][lrow] = a4.y;
        As[lk + 2][lrow] = a4.z; As[lk + 3][lrow] = a4.w;
        Bs[lk + 0][lrow] = b4.x; Bs[lk + 1][lrow] = b4.y;
        Bs[lk + 2][lrow] = b4.z; Bs[lk + 3][lrow] = b4.w;
        __syncthreads();
#pragma unroll
        for (int kk = 0; kk < 16; kk++) {
            float av[4], bv[4];
#pragma unroll
            for (int i = 0; i < 4; i++) av[i] = As[kk][ty * 4 + i];
#pragma unroll
            for (int j = 0; j < 4; j++) bv[j] = Bs[kk][tx * 4 + j];
#pragma unroll
            for (int i = 0; i < 4; i++)
#pragma unroll
                for (int j = 0; j < 4; j++) acc[i][j] += av[i] * bv[j];
        }
    }

#pragma unroll
    for (int i = 0; i < 4; i++) {
        int r = bm + ty * 4 + i;
        if (r >= M) continue;
#pragma unroll
        for (int j = 0; j < 4; j++) {
            int c = bn + tx * 4 + j;
            float v = acc[i][j] + bias[c];
            if (ACT_GELU) v = gelu_exact(v);
            C[(size_t)r * N + c] = v;
        }
    }
}

// Row L2 norms of proj_rel. grid = R_, block = 64 (one wave per row).
__global__ void rnorm_kernel(const float* __restrict__ proj, float* __restrict__ rn) {
    int r = blockIdx.x;
    int lane = threadIdx.x;
    const float* p = proj + (size_t)r * D_;
    float s = 0.f;
#pragma unroll
    for (int j = 0; j < 8; j++) { float v = p[lane + 64 * j]; s += v * v; }
#pragma unroll
    for (int off = 32; off; off >>= 1) s += __shfl_xor(s, off, 64);
    if (lane == 0) rn[r] = sqrtf(s);
}

// Per-edge: cosine sims to 32 neighbors, stable top-8 (ties -> lowest index,
// matching lax.top_k), mean-aggregate, and states init. grid = B_*E_, block=256.
__global__ void sim_topk_agg(const int* __restrict__ eids, const int* __restrict__ nids,
                             const float* __restrict__ proj, const float* __restrict__ rn,
                             float* __restrict__ agg, float* __restrict__ states) {
    int be = blockIdx.x;
    int tid = threadIdx.x;
    __shared__ float ev[512];
    __shared__ float sims[32];
    __shared__ int nid_s[32];
    __shared__ int sel[8];

    int eid = eids[be];
    const float* ep = proj + (size_t)eid * D_;
    float e0 = ep[tid], e1 = ep[tid + 256];
    ev[tid] = e0; ev[tid + 256] = e1;
    states[(size_t)be * D_ + tid] = e0;
    states[(size_t)be * D_ + tid + 256] = e1;
    if (tid < 32) nid_s[tid] = nids[be * N_ + tid];
    __syncthreads();

    int wid = tid >> 6, lane = tid & 63;
    float en = fmaxf(rn[eid], 1e-12f);
    for (int n = wid; n < N_; n += 4) {
        int nid = nid_s[n];
        const float* np = proj + (size_t)nid * D_;
        float s = 0.f;
#pragma unroll
        for (int j = 0; j < 8; j++) s += np[lane + 64 * j] * ev[lane + 64 * j];
#pragma unroll
        for (int off = 32; off; off >>= 1) s += __shfl_xor(s, off, 64);
        if (lane == 0) sims[n] = s / (fmaxf(rn[nid], 1e-12f) * en);
    }
    __syncthreads();

    if (tid == 0) {
        unsigned used = 0;
        for (int k = 0; k < K_; k++) {
            float best = -3.402823466e38f; int bi = 0;
            for (int n = 0; n < N_; n++)
                if (!((used >> n) & 1u) && sims[n] > best) { best = sims[n]; bi = n; }
            used |= 1u << bi;
            sel[k] = nid_s[bi];
        }
    }
    __syncthreads();

    float a0 = 0.f, a1 = 0.f;
#pragma unroll
    for (int k = 0; k < K_; k++) {
        const float* sp = proj + (size_t)sel[k] * D_;
        a0 += sp[tid]; a1 += sp[tid + 256];
    }
    agg[(size_t)be * D_ + tid] = a0 * 0.125f;
    agg[(size_t)be * D_ + tid + 256] = a1 * 0.125f;
}

// out[t,:] = LN(x[t,:] + y[t,:]) * g + b   (optionally * mask[t])
// grid = tokens, block = 256, D_ = 512.
__global__ void add_ln_kernel(const float* __restrict__ x, const float* __restrict__ y,
                              const float* __restrict__ g, const float* __restrict__ bb,
                              const float* __restrict__ mask, float* __restrict__ out) {
    int t = blockIdx.x;
    int tid = threadIdx.x;
    const float* xr = x + (size_t)t * D_;
    const float* yr = y + (size_t)t * D_;
    float x0 = xr[tid] + yr[tid];
    float x1 = xr[tid + 256] + yr[tid + 256];
    __shared__ float red[8];
    float s = x0 + x1;
#pragma unroll
    for (int off = 32; off; off >>= 1) s += __shfl_xor(s, off, 64);
    int wid = tid >> 6;
    if ((tid & 63) == 0) red[wid] = s;
    __syncthreads();
    float mean = (red[0] + red[1] + red[2] + red[3]) * (1.f / 512.f);
    float d0 = x0 - mean, d1 = x1 - mean;
    float v = d0 * d0 + d1 * d1;
#pragma unroll
    for (int off = 32; off; off >>= 1) v += __shfl_xor(v, off, 64);
    if ((tid & 63) == 0) red[4 + wid] = v;
    __syncthreads();
    float var = (red[4] + red[5] + red[6] + red[7]) * (1.f / 512.f);
    float rs = rsqrtf(var + 1e-5f);
    float mv = mask ? mask[t] : 1.f;
    out[(size_t)t * D_ + tid]       = (d0 * rs * g[tid] + bb[tid]) * mv;
    out[(size_t)t * D_ + tid + 256] = (d1 * rs * g[tid + 256] + bb[tid + 256]) * mv;
}

// Cross-attention: learned queries over edge states. grid = B_*M_, block = 256
// (one thread per edge). Loops 8 heads.
__global__ void mem_attn(const float* __restrict__ qb, const float* __restrict__ kb,
                         const float* __restrict__ vb, const float* __restrict__ mask,
                         float* __restrict__ mem) {
    int b = blockIdx.x >> 5;
    int m = blockIdx.x & 31;
    int tid = threadIdx.x;   // == edge index e
    __shared__ float qh[64];
    __shared__ float sc[256];
    __shared__ float red[8];
    __shared__ float oacc[4][64];

    float mk = mask[b * E_ + tid];
    for (int h = 0; h < H_; h++) {
        if (tid < 64) qh[tid] = qb[m * D_ + h * DH_ + tid];
        __syncthreads();
        const float* kr = kb + ((size_t)(b * E_ + tid)) * D_ + h * DH_;
        float s = 0.f;
#pragma unroll
        for (int d = 0; d < DH_; d += 4) {
            float4 k4 = *(const float4*)(kr + d);
            s += k4.x * qh[d] + k4.y * qh[d + 1] + k4.z * qh[d + 2] + k4.w * qh[d + 3];
        }
        s *= 0.125f;                       // 1/sqrt(64)
        if (mk == 0.f) s = -3.402823466e38f;
        float mx = s;
#pragma unroll
        for (int off = 32; off; off >>= 1) mx = fmaxf(mx, __shfl_xor(mx, off, 64));
        if ((tid & 63) == 0) red[tid >> 6] = mx;
        __syncthreads();
        mx = fmaxf(fmaxf(red[0], red[1]), fmaxf(red[2], red[3]));
        float p = expf(s - mx);
        float sum = p;
#pragma unroll
        for (int off = 32; off; off >>= 1) sum += __shfl_xor(sum, off, 64);
        if ((tid & 63) == 0) red[4 + (tid >> 6)] = sum;
        __syncthreads();
        sum = red[4] + red[5] + red[6] + red[7];
        sc[tid] = p / sum;
        __syncthreads();
        int d = tid & 63, part = tid >> 6;
        const float* vcol = vb + ((size_t)(b * E_ + part * 64)) * D_ + h * DH_ + d;
        float acc = 0.f;
#pragma unroll 8
        for (int e = 0; e < 64; e++) acc += sc[part * 64 + e] * vcol[(size_t)e * D_];
        oacc[part][d] = acc;
        __syncthreads();
        if (part == 0)
            mem[((size_t)(b * M_ + m)) * D_ + h * DH_ + d] =
                oacc[0][d] + oacc[1][d] + oacc[2][d] + oacc[3][d];
        __syncthreads();
    }
}

// Zero mem2 rows of batches with no edges. grid = B_, block = 256.
__global__ void mask_zero(const float* __restrict__ mask, float* __restrict__ mem2) {
    int b = blockIdx.x;
    int tid = threadIdx.x;
    float s = mask[b * E_ + tid];
    __shared__ float red[4];
#pragma unroll
    for (int off = 32; off; off >>= 1) s += __shfl_xor(s, off, 64);
    if ((tid & 63) == 0) red[tid >> 6] = s;
    __syncthreads();
    float tot = red[0] + red[1] + red[2] + red[3];
    if (tot == 0.f) {
        for (int i = tid; i < M_ * D_; i += 256)
            mem2[(size_t)b * M_ * D_ + i] = 0.f;
    }
}

extern "C" void kernel_launch(void* const* d_in, const int* in_sizes, int n_in,
                              void* d_out, int out_size, void* d_ws, size_t ws_size,
                              hipStream_t stream) {
    // Inputs: float32 tensors (per reference jnp.float32) + int32 id tensors.
    // Output: float32 [B, M, HLLM].
    const int*   edge_rel_ids     = (const int*)d_in[0];
    const int*   neighbor_rel_ids = (const int*)d_in[1];
    const float* edge_mask        = (const float*)d_in[2];
    const float* rel_emb          = (const float*)d_in[3];
    const float* rp_w             = (const float*)d_in[4];
    const float* rp_b             = (const float*)d_in[5];
    const float* ly_vw            = (const float*)d_in[6];
    const float* ly_vb            = (const float*)d_in[7];
    const float* ly_ow            = (const float*)d_in[8];
    const float* ly_ob            = (const float*)d_in[9];
    const float* ly_n1g           = (const float*)d_in[10];
    const float* ly_n1b           = (const float*)d_in[11];
    const float* ly_n2g           = (const float*)d_in[12];
    const float* ly_n2b           = (const float*)d_in[13];
    const float* ly_w1            = (const float*)d_in[14];
    const float* ly_b1            = (const float*)d_in[15];
    const float* ly_w2            = (const float*)d_in[16];
    const float* ly_b2            = (const float*)d_in[17];
    const float* mem_q            = (const float*)d_in[18];
    const float* t_qw             = (const float*)d_in[19];
    const float* t_qb             = (const float*)d_in[20];
    const float* t_kw             = (const float*)d_in[21];
    const float* t_kb             = (const float*)d_in[22];
    const float* t_vw             = (const float*)d_in[23];
    const float* t_vb             = (const float*)d_in[24];
    const float* t_ow             = (const float*)d_in[25];
    const float* t_ob             = (const float*)d_in[26];
    const float* proj_w           = (const float*)d_in[27];
    const float* proj_b           = (const float*)d_in[28];

    float* out = (float*)d_out;   // fp32 output

    // workspace carve-up (fp32), 64-float aligned chunks. Total ~38.8 MB.
    float* ws = (float*)d_ws;
    size_t off = 0;
    auto alloc = [&](size_t n) { float* p = ws + off; off += (n + 63) & ~(size_t)63; return p; };
    float* proj   = alloc((size_t)R_ * D_);       // 2000x512
    float* rn     = alloc(R_);
    float* states = alloc((size_t)B_ * E_ * D_);  // 2048x512
    float* agg    = alloc((size_t)B_ * E_ * D_);
    float* tmpA   = alloc((size_t)B_ * E_ * D_);
    float* tmpB   = alloc((size_t)B_ * E_ * D_);
    float* ff1    = alloc((size_t)B_ * E_ * 4 * D_); // 2048x2048
    float* qbuf   = alloc((size_t)M_ * D_);
    float* memb   = alloc((size_t)B_ * M_ * D_);
    float* mem2   = alloc((size_t)B_ * M_ * D_);
    float* kbuf = tmpA;   // reuse: tmpA/tmpB dead after the layer stack
    float* vbuf = tmpB;
    (void)ws_size; (void)in_sizes; (void)n_in; (void)out_size;

    const int T = B_ * E_;   // 2048 tokens

    // 1. proj_rel = rel_emb @ rp_w^T + rp_b   [2000,512]
    gemm_nt<0><<<dim3(D_ / 64, (R_ + 63) / 64), 256, 0, stream>>>(
        rel_emb, rp_w, rp_b, proj, R_, D_, RD_);
    // 2. per-relation norms
    rnorm_kernel<<<R_, 64, 0, stream>>>(proj, rn);
    // 3. sims + top-k + aggregate, states init
    sim_topk_agg<<<T, 256, 0, stream>>>(edge_rel_ids, neighbor_rel_ids, proj, rn, agg, states);

    // 4. relation-context layers
    for (int l = 0; l < L_; l++) {
        const float* vw = ly_vw + (size_t)l * D_ * D_;
        const float* vb = ly_vb + (size_t)l * D_;
        const float* ow = ly_ow + (size_t)l * D_ * D_;
        const float* ob = ly_ob + (size_t)l * D_;
        const float* n1g = ly_n1g + (size_t)l * D_;
        const float* n1b = ly_n1b + (size_t)l * D_;
        const float* n2g = ly_n2g + (size_t)l * D_;
        const float* n2b = ly_n2b + (size_t)l * D_;
        const float* w1 = ly_w1 + (size_t)l * 4 * D_ * D_;
        const float* b1 = ly_b1 + (size_t)l * 4 * D_;
        const float* w2 = ly_w2 + (size_t)l * D_ * 4 * D_;
        const float* b2 = ly_b2 + (size_t)l * D_;

        gemm_nt<0><<<dim3(D_ / 64, T / 64), 256, 0, stream>>>(agg,  vw, vb, tmpA, T, D_, D_);
        gemm_nt<0><<<dim3(D_ / 64, T / 64), 256, 0, stream>>>(tmpA, ow, ob, tmpB, T, D_, D_);
        add_ln_kernel<<<T, 256, 0, stream>>>(states, tmpB, n1g, n1b, nullptr, states);
        gemm_nt<1><<<dim3(4 * D_ / 64, T / 64), 256, 0, stream>>>(states, w1, b1, ff1, T, 4 * D_, D_);
        gemm_nt<0><<<dim3(D_ / 64, T / 64), 256, 0, stream>>>(ff1, w2, b2, tmpB, T, D_, 4 * D_);
        add_ln_kernel<<<T, 256, 0, stream>>>(states, tmpB, n2g, n2b, edge_mask, states);
    }

    // 5. q/k/v projections  (kbuf aliases tmpA, vbuf aliases tmpB — both dead now)
    gemm_nt<0><<<dim3(D_ / 64, T / 64), 256, 0, stream>>>(states, t_kw, t_kb, kbuf, T, D_, D_);
    gemm_nt<0><<<dim3(D_ / 64, T / 64), 256, 0, stream>>>(states, t_vw, t_vb, vbuf, T, D_, D_);
    gemm_nt<0><<<dim3(D_ / 64, 1), 256, 0, stream>>>(mem_q, t_qw, t_qb, qbuf, M_, D_, D_);

    // 6. memory cross-attention -> memb [B,M,D]
    mem_attn<<<B_ * M_, 256, 0, stream>>>(qbuf, kbuf, vbuf, edge_mask, memb);

    // 7. output proj of attention + no-edge zeroing
    gemm_nt<0><<<dim3(D_ / 64, (B_ * M_) / 64), 256, 0, stream>>>(
        memb, t_ow, t_ob, mem2, B_ * M_, D_, D_);
    mask_zero<<<B_, 256, 0, stream>>>(edge_mask, mem2);

    // 8. final LLM projection (fp32 out)
    gemm_nt<0><<<dim3(HL_ / 64, (B_ * M_) / 64), 256, 0, stream>>>(
        mem2, proj_w, proj_b, out, B_ * M_, HL_, D_);
}

// Round 4
// 540.659 us; speedup vs baseline: 1.9803x; 1.9803x over previous
//
#include <hip/hip_runtime.h>
#include <hip/hip_bf16.h>
#include <math.h>

// Problem constants (from reference)
#define B_   8
#define E_   256
#define N_   32
#define D_   512
#define RD_  768
#define R_   2000
#define L_   2
#define K_   8
#define M_   32
#define H_   8
#define DH_  64
#define HL_  4096

typedef float f32x4 __attribute__((ext_vector_type(4)));
typedef __bf16 bf16x8 __attribute__((ext_vector_type(8)));

__device__ __forceinline__ float gelu_exact(float x) {
    return 0.5f * x * (1.0f + erff(x * 0.70710678118654752f));
}

__device__ __forceinline__ unsigned short f2bf(float x) {
    return __hip_bfloat16_raw(__float2bfloat16(x)).x;
}

// ---------------------------------------------------------------------------
// fp32 fallback GEMM (small/exact shapes): C[M,N] = A @ B[N,K]^T + bias.
// 64x64 tile, BK=16, 256 threads. Used for proj (exact topk path) + tiny GEMMs.
// ---------------------------------------------------------------------------
template <int ACT_GELU>
__global__ void gemm_nt(const float* __restrict__ A, const float* __restrict__ Bm,
                        const float* __restrict__ bias, float* __restrict__ C,
                        int M, int N, int K) {
    __shared__ float As[16][65];
    __shared__ float Bs[16][65];
    const int tid = threadIdx.x;
    const int bm = blockIdx.y * 64, bn = blockIdx.x * 64;
    const int tx = tid & 15, ty = tid >> 4;
    const int lrow = tid >> 2;
    const int lk = (tid & 3) << 2;

    float acc[4][4] = {{0.f}};
    const int arow = bm + lrow;
    const int brow = bn + lrow;

    for (int k0 = 0; k0 < K; k0 += 16) {
        float4 a4 = make_float4(0.f, 0.f, 0.f, 0.f);
        if (arow < M) a4 = *(const float4*)(A + (size_t)arow * K + k0 + lk);
        float4 b4 = *(const float4*)(Bm + (size_t)brow * K + k0 + lk);
        __syncthreads();
        As[lk + 0][lrow] = a4.x; As[lk + 1][lrow] = a4.y;
        As[lk + 2][lrow] = a4.z; As[lk + 3][lrow] = a4.w;
        Bs[lk + 0][lrow] = b4.x; Bs[lk + 1][lrow] = b4.y;
        Bs[lk + 2][lrow] = b4.z; Bs[lk + 3][lrow] = b4.w;
        __syncthreads();
#pragma unroll
        for (int kk = 0; kk < 16; kk++) {
            float av[4], bv[4];
#pragma unroll
            for (int i = 0; i < 4; i++) av[i] = As[kk][ty * 4 + i];
#pragma unroll
            for (int j = 0; j < 4; j++) bv[j] = Bs[kk][tx * 4 + j];
#pragma unroll
            for (int i = 0; i < 4; i++)
#pragma unroll
                for (int j = 0; j < 4; j++) acc[i][j] += av[i] * bv[j];
        }
    }

#pragma unroll
    for (int i = 0; i < 4; i++) {
        int r = bm + ty * 4 + i;
        if (r >= M) continue;
#pragma unroll
        for (int j = 0; j < 4; j++) {
            int c = bn + tx * 4 + j;
            float v = acc[i][j] + bias[c];
            if (ACT_GELU) v = gelu_exact(v);
            C[(size_t)r * N + c] = v;
        }
    }
}

// ---------------------------------------------------------------------------
// bf16 MFMA GEMM: C[M,N] = A[M,K](bf16) @ W[N,K](bf16)^T + bias(f32).
// TMxTN tile, BK=32, 256 threads (4 waves, 2x2 wave grid, each wave
// (TM/2)x(TN/2) via RMxRN tiles of v_mfma_f32_16x16x32_bf16).
// Requires M%TM==0, N%TN==0, K%32==0 (holds at every call site).
// Fragment layouts (m89/m91/m120-verified): A: m=lane&15, k=quad*8+j;
// B(=W row): n=lane&15, k=quad*8+j; D: col=lane&15, row=quad*4+reg.
// ---------------------------------------------------------------------------
template <int TM, int TN, int ACT_GELU, int OUT_BF16>
__global__ __launch_bounds__(256) void gemm_mfma(const unsigned short* __restrict__ A,
                                                 const unsigned short* __restrict__ W,
                                                 const float* __restrict__ bias,
                                                 void* __restrict__ Cv,
                                                 int M, int N, int K) {
    constexpr int WTM = TM / 2, WTN = TN / 2;
    constexpr int RM = WTM / 16, RN = WTN / 16;
    __shared__ __align__(16) unsigned short As[TM * 32];
    __shared__ __align__(16) unsigned short Bs[TN * 32];

    const int tid = threadIdx.x;
    const int wave = tid >> 6, lane = tid & 63;
    const int quad = lane >> 4, l16 = lane & 15;
    const int wm = wave >> 1, wn = wave & 1;
    const int bm = blockIdx.y * TM, bn = blockIdx.x * TN;
    (void)M;

    f32x4 acc[RM][RN];
#pragma unroll
    for (int i = 0; i < RM; i++)
#pragma unroll
        for (int j = 0; j < RN; j++) acc[i][j] = (f32x4){0.f, 0.f, 0.f, 0.f};

    for (int k0 = 0; k0 < K; k0 += 32) {
        __syncthreads();
#pragma unroll
        for (int c = tid; c < TM * 4; c += 256) {
            int row = c >> 2, seg = c & 3;
            *(uint4*)(&As[row * 32 + seg * 8]) =
                *(const uint4*)(A + (size_t)(bm + row) * K + k0 + seg * 8);
        }
#pragma unroll
        for (int c = tid; c < TN * 4; c += 256) {
            int row = c >> 2, seg = c & 3;
            *(uint4*)(&Bs[row * 32 + seg * 8]) =
                *(const uint4*)(W + (size_t)(bn + row) * K + k0 + seg * 8);
        }
        __syncthreads();
        bf16x8 af[RM], bf[RN];
#pragma unroll
        for (int i = 0; i < RM; i++)
            af[i] = *(const bf16x8*)(&As[(wm * WTM + i * 16 + l16) * 32 + quad * 8]);
#pragma unroll
        for (int j = 0; j < RN; j++)
            bf[j] = *(const bf16x8*)(&Bs[(wn * WTN + j * 16 + l16) * 32 + quad * 8]);
#pragma unroll
        for (int i = 0; i < RM; i++)
#pragma unroll
            for (int j = 0; j < RN; j++)
                acc[i][j] = __builtin_amdgcn_mfma_f32_16x16x32_bf16(af[i], bf[j], acc[i][j], 0, 0, 0);
    }

#pragma unroll
    for (int i = 0; i < RM; i++) {
#pragma unroll
        for (int j = 0; j < RN; j++) {
            int c = bn + wn * WTN + j * 16 + l16;
            float bv = bias[c];
#pragma unroll
            for (int reg = 0; reg < 4; reg++) {
                int r = bm + wm * WTM + i * 16 + quad * 4 + reg;
                float v = acc[i][j][reg] + bv;
                if (ACT_GELU) v = gelu_exact(v);
                if (OUT_BF16)
                    ((unsigned short*)Cv)[(size_t)r * N + c] = f2bf(v);
                else
                    ((float*)Cv)[(size_t)r * N + c] = v;
            }
        }
    }
}

// f32 -> bf16 conversion, 4 elements/thread. n must be %4.
__global__ void cvt_bf16(const float* __restrict__ src, unsigned short* __restrict__ dst, int n4) {
    int i = blockIdx.x * 256 + threadIdx.x;
    if (i < n4) {
        float4 v = ((const float4*)src)[i];
        ushort4 o;
        o.x = f2bf(v.x); o.y = f2bf(v.y); o.z = f2bf(v.z); o.w = f2bf(v.w);
        ((ushort4*)dst)[i] = o;
    }
}

// Row L2 norms of proj_rel. grid = R_, block = 64.
__global__ void rnorm_kernel(const float* __restrict__ proj, float* __restrict__ rn) {
    int r = blockIdx.x;
    int lane = threadIdx.x;
    const float* p = proj + (size_t)r * D_;
    float s = 0.f;
#pragma unroll
    for (int j = 0; j < 8; j++) { float v = p[lane + 64 * j]; s += v * v; }
#pragma unroll
    for (int off = 32; off; off >>= 1) s += __shfl_xor(s, off, 64);
    if (lane == 0) rn[r] = sqrtf(s);
}

// Per-edge: cosine sims (exact f32 -> exact topk), mean-aggregate, states init.
// Writes agg f32 + bf16 shadow. grid = B_*E_, block = 256.
__global__ void sim_topk_agg(const int* __restrict__ eids, const int* __restrict__ nids,
                             const float* __restrict__ proj, const float* __restrict__ rn,
                             float* __restrict__ agg, unsigned short* __restrict__ agg_bf,
                             float* __restrict__ states) {
    int be = blockIdx.x;
    int tid = threadIdx.x;
    __shared__ float ev[512];
    __shared__ float sims[32];
    __shared__ int nid_s[32];
    __shared__ int sel[8];

    int eid = eids[be];
    const float* ep = proj + (size_t)eid * D_;
    float e0 = ep[tid], e1 = ep[tid + 256];
    ev[tid] = e0; ev[tid + 256] = e1;
    states[(size_t)be * D_ + tid] = e0;
    states[(size_t)be * D_ + tid + 256] = e1;
    if (tid < 32) nid_s[tid] = nids[be * N_ + tid];
    __syncthreads();

    int wid = tid >> 6, lane = tid & 63;
    float en = fmaxf(rn[eid], 1e-12f);
    for (int n = wid; n < N_; n += 4) {
        int nid = nid_s[n];
        const float* np = proj + (size_t)nid * D_;
        float s = 0.f;
#pragma unroll
        for (int j = 0; j < 8; j++) s += np[lane + 64 * j] * ev[lane + 64 * j];
#pragma unroll
        for (int off = 32; off; off >>= 1) s += __shfl_xor(s, off, 64);
        if (lane == 0) sims[n] = s / (fmaxf(rn[nid], 1e-12f) * en);
    }
    __syncthreads();

    if (tid == 0) {
        unsigned used = 0;
        for (int k = 0; k < K_; k++) {
            float best = -3.402823466e38f; int bi = 0;
            for (int n = 0; n < N_; n++)
                if (!((used >> n) & 1u) && sims[n] > best) { best = sims[n]; bi = n; }
            used |= 1u << bi;
            sel[k] = nid_s[bi];
        }
    }
    __syncthreads();

    float a0 = 0.f, a1 = 0.f;
#pragma unroll
    for (int k = 0; k < K_; k++) {
        const float* sp = proj + (size_t)sel[k] * D_;
        a0 += sp[tid]; a1 += sp[tid + 256];
    }
    a0 *= 0.125f; a1 *= 0.125f;
    agg[(size_t)be * D_ + tid] = a0;
    agg[(size_t)be * D_ + tid + 256] = a1;
    agg_bf[(size_t)be * D_ + tid] = f2bf(a0);
    agg_bf[(size_t)be * D_ + tid + 256] = f2bf(a1);
}

// out = LN(x + y) * g + b (optionally * mask[t]); writes f32 + bf16 shadow.
__global__ void add_ln_kernel(const float* __restrict__ x, const float* __restrict__ y,
                              const float* __restrict__ g, const float* __restrict__ bb,
                              const float* __restrict__ mask, float* __restrict__ out,
                              unsigned short* __restrict__ out_bf) {
    int t = blockIdx.x;
    int tid = threadIdx.x;
    const float* xr = x + (size_t)t * D_;
    const float* yr = y + (size_t)t * D_;
    float x0 = xr[tid] + yr[tid];
    float x1 = xr[tid + 256] + yr[tid + 256];
    __shared__ float red[8];
    float s = x0 + x1;
#pragma unroll
    for (int off = 32; off; off >>= 1) s += __shfl_xor(s, off, 64);
    int wid = tid >> 6;
    if ((tid & 63) == 0) red[wid] = s;
    __syncthreads();
    float mean = (red[0] + red[1] + red[2] + red[3]) * (1.f / 512.f);
    float d0 = x0 - mean, d1 = x1 - mean;
    float v = d0 * d0 + d1 * d1;
#pragma unroll
    for (int off = 32; off; off >>= 1) v += __shfl_xor(v, off, 64);
    if ((tid & 63) == 0) red[4 + wid] = v;
    __syncthreads();
    float var = (red[4] + red[5] + red[6] + red[7]) * (1.f / 512.f);
    float rs = rsqrtf(var + 1e-5f);
    float mv = mask ? mask[t] : 1.f;
    float o0 = (d0 * rs * g[tid] + bb[tid]) * mv;
    float o1 = (d1 * rs * g[tid + 256] + bb[tid + 256]) * mv;
    out[(size_t)t * D_ + tid] = o0;
    out[(size_t)t * D_ + tid + 256] = o1;
    out_bf[(size_t)t * D_ + tid] = f2bf(o0);
    out_bf[(size_t)t * D_ + tid + 256] = f2bf(o1);
}

// Cross-attention: grid = B_*M_, block = 256 (thread = edge). Loops 8 heads.
__global__ void mem_attn(const float* __restrict__ qb, const float* __restrict__ kb,
                         const float* __restrict__ vb, const float* __restrict__ mask,
                         float* __restrict__ mem) {
    int b = blockIdx.x >> 5;
    int m = blockIdx.x & 31;
    int tid = threadIdx.x;
    __shared__ float qh[64];
    __shared__ float sc[256];
    __shared__ float red[8];
    __shared__ float oacc[4][64];

    float mk = mask[b * E_ + tid];
    for (int h = 0; h < H_; h++) {
        if (tid < 64) qh[tid] = qb[m * D_ + h * DH_ + tid];
        __syncthreads();
        const float* kr = kb + ((size_t)(b * E_ + tid)) * D_ + h * DH_;
        float s = 0.f;
#pragma unroll
        for (int d = 0; d < DH_; d += 4) {
            float4 k4 = *(const float4*)(kr + d);
            s += k4.x * qh[d] + k4.y * qh[d + 1] + k4.z * qh[d + 2] + k4.w * qh[d + 3];
        }
        s *= 0.125f;
        if (mk == 0.f) s = -3.402823466e38f;
        float mx = s;
#pragma unroll
        for (int off = 32; off; off >>= 1) mx = fmaxf(mx, __shfl_xor(mx, off, 64));
        if ((tid & 63) == 0) red[tid >> 6] = mx;
        __syncthreads();
        mx = fmaxf(fmaxf(red[0], red[1]), fmaxf(red[2], red[3]));
        float p = expf(s - mx);
        float sum = p;
#pragma unroll
        for (int off = 32; off; off >>= 1) sum += __shfl_xor(sum, off, 64);
        if ((tid & 63) == 0) red[4 + (tid >> 6)] = sum;
        __syncthreads();
        sum = red[4] + red[5] + red[6] + red[7];
        sc[tid] = p / sum;
        __syncthreads();
        int d = tid & 63, part = tid >> 6;
        const float* vcol = vb + ((size_t)(b * E_ + part * 64)) * D_ + h * DH_ + d;
        float acc = 0.f;
#pragma unroll 8
        for (int e = 0; e < 64; e++) acc += sc[part * 64 + e] * vcol[(size_t)e * D_];
        oacc[part][d] = acc;
        __syncthreads();
        if (part == 0)
            mem[((size_t)(b * M_ + m)) * D_ + h * DH_ + d] =
                oacc[0][d] + oacc[1][d] + oacc[2][d] + oacc[3][d];
        __syncthreads();
    }
}

// Zero mem2 rows of batches with no edges. grid = B_, block = 256.
__global__ void mask_zero(const float* __restrict__ mask, float* __restrict__ mem2) {
    int b = blockIdx.x;
    int tid = threadIdx.x;
    float s = mask[b * E_ + tid];
    __shared__ float red[4];
#pragma unroll
    for (int off = 32; off; off >>= 1) s += __shfl_xor(s, off, 64);
    if ((tid & 63) == 0) red[tid >> 6] = s;
    __syncthreads();
    float tot = red[0] + red[1] + red[2] + red[3];
    if (tot == 0.f) {
        for (int i = tid; i < M_ * D_; i += 256)
            mem2[(size_t)b * M_ * D_ + i] = 0.f;
    }
}

extern "C" void kernel_launch(void* const* d_in, const int* in_sizes, int n_in,
                              void* d_out, int out_size, void* d_ws, size_t ws_size,
                              hipStream_t stream) {
    const int*   edge_rel_ids     = (const int*)d_in[0];
    const int*   neighbor_rel_ids = (const int*)d_in[1];
    const float* edge_mask        = (const float*)d_in[2];
    const float* rel_emb          = (const float*)d_in[3];
    const float* rp_w             = (const float*)d_in[4];
    const float* rp_b             = (const float*)d_in[5];
    const float* ly_vw            = (const float*)d_in[6];
    const float* ly_vb            = (const float*)d_in[7];
    const float* ly_ow            = (const float*)d_in[8];
    const float* ly_ob            = (const float*)d_in[9];
    const float* ly_n1g           = (const float*)d_in[10];
    const float* ly_n1b           = (const float*)d_in[11];
    const float* ly_n2g           = (const float*)d_in[12];
    const float* ly_n2b           = (const float*)d_in[13];
    const float* ly_w1            = (const float*)d_in[14];
    const float* ly_b1            = (const float*)d_in[15];
    const float* ly_w2            = (const float*)d_in[16];
    const float* ly_b2            = (const float*)d_in[17];
    const float* mem_q            = (const float*)d_in[18];
    const float* t_qw             = (const float*)d_in[19];
    const float* t_qb             = (const float*)d_in[20];
    const float* t_kw             = (const float*)d_in[21];
    const float* t_kb             = (const float*)d_in[22];
    const float* t_vw             = (const float*)d_in[23];
    const float* t_vb             = (const float*)d_in[24];
    const float* t_ow             = (const float*)d_in[25];
    const float* t_ob             = (const float*)d_in[26];
    const float* proj_w           = (const float*)d_in[27];
    const float* proj_b           = (const float*)d_in[28];

    float* out = (float*)d_out;

    // byte-based workspace carve-up, 256-B aligned chunks
    char* ws = (char*)d_ws;
    size_t off = 0;
    auto allocf = [&](size_t n) { float* p = (float*)(ws + off); off += ((n * 4 + 255) & ~(size_t)255); return p; };
    auto allocb = [&](size_t n) { unsigned short* p = (unsigned short*)(ws + off); off += ((n * 2 + 255) & ~(size_t)255); return p; };

    const int T = B_ * E_;   // 2048 tokens

    float* proj   = allocf((size_t)R_ * D_);
    float* rn     = allocf(R_);
    float* states = allocf((size_t)T * D_);
    float* agg    = allocf((size_t)T * D_);
    float* tmpB   = allocf((size_t)T * D_);
    float* kbuf   = allocf((size_t)T * D_);
    float* vbuf   = allocf((size_t)T * D_);
    float* qbuf   = allocf((size_t)M_ * D_);
    float* memb   = allocf((size_t)B_ * M_ * D_);
    float* mem2   = allocf((size_t)B_ * M_ * D_);

    unsigned short* agg_bf    = allocb((size_t)T * D_);
    unsigned short* states_bf = allocb((size_t)T * D_);
    unsigned short* tmpA_bf   = allocb((size_t)T * D_);
    unsigned short* ff1_bf    = allocb((size_t)T * 4 * D_);
    unsigned short* mem2_bf   = allocb((size_t)B_ * M_ * D_);
    unsigned short* vw_bf     = allocb((size_t)L_ * D_ * D_);
    unsigned short* ow_bf     = allocb((size_t)L_ * D_ * D_);
    unsigned short* w1_bf     = allocb((size_t)L_ * 4 * D_ * D_);
    unsigned short* w2_bf     = allocb((size_t)L_ * 4 * D_ * D_);
    unsigned short* kw_bf     = allocb((size_t)D_ * D_);
    unsigned short* vw2_bf    = allocb((size_t)D_ * D_);
    unsigned short* pw_bf     = allocb((size_t)HL_ * D_);
    (void)ws_size; (void)in_sizes; (void)n_in; (void)out_size;

    // 0. weight conversions f32 -> bf16 (ws is re-poisoned every call)
    auto cvt = [&](const float* s, unsigned short* d, size_t n) {
        int n4 = (int)(n / 4);
        cvt_bf16<<<(n4 + 255) / 256, 256, 0, stream>>>(s, d, n4);
    };
    cvt(ly_vw, vw_bf, (size_t)L_ * D_ * D_);
    cvt(ly_ow, ow_bf, (size_t)L_ * D_ * D_);
    cvt(ly_w1, w1_bf, (size_t)L_ * 4 * D_ * D_);
    cvt(ly_w2, w2_bf, (size_t)L_ * 4 * D_ * D_);
    cvt(t_kw,  kw_bf, (size_t)D_ * D_);
    cvt(t_vw,  vw2_bf, (size_t)D_ * D_);
    cvt(proj_w, pw_bf, (size_t)HL_ * D_);

    // 1. proj_rel = rel_emb @ rp_w^T + rp_b  (exact f32 — feeds topk selection)
    gemm_nt<0><<<dim3(D_ / 64, (R_ + 63) / 64), 256, 0, stream>>>(
        rel_emb, rp_w, rp_b, proj, R_, D_, RD_);
    // 2. per-relation norms
    rnorm_kernel<<<R_, 64, 0, stream>>>(proj, rn);
    // 3. sims + exact top-k + aggregate, states init
    sim_topk_agg<<<T, 256, 0, stream>>>(edge_rel_ids, neighbor_rel_ids, proj, rn,
                                        agg, agg_bf, states);

    // 4. relation-context layers (bf16 MFMA GEMMs, f32 LN/residual)
    for (int l = 0; l < L_; l++) {
        const unsigned short* vw = vw_bf + (size_t)l * D_ * D_;
        const unsigned short* ow = ow_bf + (size_t)l * D_ * D_;
        const unsigned short* w1 = w1_bf + (size_t)l * 4 * D_ * D_;
        const unsigned short* w2 = w2_bf + (size_t)l * D_ * 4 * D_;
        const float* vb = ly_vb + (size_t)l * D_;
        const float* ob = ly_ob + (size_t)l * D_;
        const float* b1 = ly_b1 + (size_t)l * 4 * D_;
        const float* b2 = ly_b2 + (size_t)l * D_;
        const float* n1g = ly_n1g + (size_t)l * D_;
        const float* n1b = ly_n1b + (size_t)l * D_;
        const float* n2g = ly_n2g + (size_t)l * D_;
        const float* n2b = ly_n2b + (size_t)l * D_;

        // attn = ow(vw(agg))
        gemm_mfma<64, 64, 0, 1><<<dim3(D_ / 64, T / 64), 256, 0, stream>>>(
            agg_bf, vw, vb, tmpA_bf, T, D_, D_);
        gemm_mfma<64, 64, 0, 0><<<dim3(D_ / 64, T / 64), 256, 0, stream>>>(
            tmpA_bf, ow, ob, tmpB, T, D_, D_);
        add_ln_kernel<<<T, 256, 0, stream>>>(states, tmpB, n1g, n1b, nullptr,
                                             states, states_bf);
        // ff
        gemm_mfma<128, 128, 1, 1><<<dim3(4 * D_ / 128, T / 128), 256, 0, stream>>>(
            states_bf, w1, b1, ff1_bf, T, 4 * D_, D_);
        gemm_mfma<64, 64, 0, 0><<<dim3(D_ / 64, T / 64), 256, 0, stream>>>(
            ff1_bf, w2, b2, tmpB, T, D_, 4 * D_);
        add_ln_kernel<<<T, 256, 0, stream>>>(states, tmpB, n2g, n2b, edge_mask,
                                             states, states_bf);
    }

    // 5. q/k/v projections
    gemm_mfma<64, 64, 0, 0><<<dim3(D_ / 64, T / 64), 256, 0, stream>>>(
        states_bf, kw_bf, t_kb, kbuf, T, D_, D_);
    gemm_mfma<64, 64, 0, 0><<<dim3(D_ / 64, T / 64), 256, 0, stream>>>(
        states_bf, vw2_bf, t_vb, vbuf, T, D_, D_);
    gemm_nt<0><<<dim3(D_ / 64, 1), 256, 0, stream>>>(mem_q, t_qw, t_qb, qbuf, M_, D_, D_);

    // 6. memory cross-attention
    mem_attn<<<B_ * M_, 256, 0, stream>>>(qbuf, kbuf, vbuf, edge_mask, memb);

    // 7. output proj + no-edge zeroing + bf16 shadow
    gemm_nt<0><<<dim3(D_ / 64, (B_ * M_) / 64), 256, 0, stream>>>(
        memb, t_ow, t_ob, mem2, B_ * M_, D_, D_);
    mask_zero<<<B_, 256, 0, stream>>>(edge_mask, mem2);
    cvt(mem2, mem2_bf, (size_t)B_ * M_ * D_);

    // 8. final LLM projection (bf16 MFMA, f32 out)
    gemm_mfma<64, 64, 0, 0><<<dim3(HL_ / 64, (B_ * M_) / 64), 256, 0, stream>>>(
        mem2_bf, pw_bf, proj_b, out, B_ * M_, HL_, D_);
}

// Round 5
// 460.437 us; speedup vs baseline: 2.3253x; 1.1742x over previous
//
#include <hip/hip_runtime.h>
#include <hip/hip_bf16.h>
#include <math.h>

#define B_   8
#define E_   256
#define N_   32
#define D_   512
#define RD_  768
#define R_   2000
#define L_   2
#define K_   8
#define M_   32
#define H_   8
#define DH_  64
#define HL_  4096

typedef float f32x4 __attribute__((ext_vector_type(4)));
typedef __bf16 bf16x8 __attribute__((ext_vector_type(8)));

__device__ __forceinline__ float gelu_exact(float x) {
    return 0.5f * x * (1.0f + erff(x * 0.70710678118654752f));
}
__device__ __forceinline__ unsigned short f2bf(float x) {
    return __hip_bfloat16_raw(__float2bfloat16(x)).x;
}

// ---------------------------------------------------------------------------
// bf16 MFMA GEMM: C[M,N] = A[M,K](bf16) @ W[N,K](bf16)^T [+ bias(f32)].
// TMxTN tile, BK=32, 256 threads (2x2 waves, each (TM/2)x(TN/2) of
// v_mfma_f32_16x16x32_bf16). Stores guarded by r<M; A-loads unguarded (caller
// pads A allocation to a TM multiple of rows). N%TN==0, K%32==0.
// ---------------------------------------------------------------------------
template <int TM, int TN, int ACT_GELU, int OUT_BF16, int HAS_BIAS>
__global__ __launch_bounds__(256) void gemm_mfma(const unsigned short* __restrict__ A,
                                                 const unsigned short* __restrict__ W,
                                                 const float* __restrict__ bias,
                                                 void* __restrict__ Cv,
                                                 int M, int N, int K) {
    constexpr int WTM = TM / 2, WTN = TN / 2;
    constexpr int RM = WTM / 16, RN = WTN / 16;
    __shared__ __align__(16) unsigned short As[TM * 32];
    __shared__ __align__(16) unsigned short Bs[TN * 32];

    const int tid = threadIdx.x;
    const int wave = tid >> 6, lane = tid & 63;
    const int quad = lane >> 4, l16 = lane & 15;
    const int wm = wave >> 1, wn = wave & 1;
    const int bm = blockIdx.y * TM, bn = blockIdx.x * TN;

    f32x4 acc[RM][RN];
#pragma unroll
    for (int i = 0; i < RM; i++)
#pragma unroll
        for (int j = 0; j < RN; j++) acc[i][j] = (f32x4){0.f, 0.f, 0.f, 0.f};

    for (int k0 = 0; k0 < K; k0 += 32) {
        __syncthreads();
#pragma unroll
        for (int c = tid; c < TM * 4; c += 256) {
            int row = c >> 2, seg = c & 3;
            *(uint4*)(&As[row * 32 + seg * 8]) =
                *(const uint4*)(A + (size_t)(bm + row) * K + k0 + seg * 8);
        }
#pragma unroll
        for (int c = tid; c < TN * 4; c += 256) {
            int row = c >> 2, seg = c & 3;
            *(uint4*)(&Bs[row * 32 + seg * 8]) =
                *(const uint4*)(W + (size_t)(bn + row) * K + k0 + seg * 8);
        }
        __syncthreads();
        bf16x8 af[RM], bf[RN];
#pragma unroll
        for (int i = 0; i < RM; i++)
            af[i] = *(const bf16x8*)(&As[(wm * WTM + i * 16 + l16) * 32 + quad * 8]);
#pragma unroll
        for (int j = 0; j < RN; j++)
            bf[j] = *(const bf16x8*)(&Bs[(wn * WTN + j * 16 + l16) * 32 + quad * 8]);
#pragma unroll
        for (int i = 0; i < RM; i++)
#pragma unroll
            for (int j = 0; j < RN; j++)
                acc[i][j] = __builtin_amdgcn_mfma_f32_16x16x32_bf16(af[i], bf[j], acc[i][j], 0, 0, 0);
    }

#pragma unroll
    for (int i = 0; i < RM; i++) {
#pragma unroll
        for (int j = 0; j < RN; j++) {
            int c = bn + wn * WTN + j * 16 + l16;
            float bv = HAS_BIAS ? bias[c] : 0.f;
#pragma unroll
            for (int reg = 0; reg < 4; reg++) {
                int r = bm + wm * WTM + i * 16 + quad * 4 + reg;
                if (r < M) {
                    float v = acc[i][j][reg] + bv;
                    if (ACT_GELU) v = gelu_exact(v);
                    if (OUT_BF16)
                        ((unsigned short*)Cv)[(size_t)r * N + c] = f2bf(v);
                    else
                        ((float*)Cv)[(size_t)r * N + c] = v;
                }
            }
        }
    }
}

// fp32 GEMM (tiny shapes only): C = A @ B^T + bias. 64x64 tile.
__global__ void gemm_nt(const float* __restrict__ A, const float* __restrict__ Bm,
                        const float* __restrict__ bias, float* __restrict__ C,
                        int M, int N, int K) {
    __shared__ float As[16][65];
    __shared__ float Bs[16][65];
    const int tid = threadIdx.x;
    const int bm = blockIdx.y * 64, bn = blockIdx.x * 64;
    const int tx = tid & 15, ty = tid >> 4;
    const int lrow = tid >> 2, lk = (tid & 3) << 2;
    float acc[4][4] = {{0.f}};
    const int arow = bm + lrow, brow = bn + lrow;
    for (int k0 = 0; k0 < K; k0 += 16) {
        float4 a4 = make_float4(0.f, 0.f, 0.f, 0.f);
        if (arow < M) a4 = *(const float4*)(A + (size_t)arow * K + k0 + lk);
        float4 b4 = *(const float4*)(Bm + (size_t)brow * K + k0 + lk);
        __syncthreads();
        As[lk + 0][lrow] = a4.x; As[lk + 1][lrow] = a4.y;
        As[lk + 2][lrow] = a4.z; As[lk + 3][lrow] = a4.w;
        Bs[lk + 0][lrow] = b4.x; Bs[lk + 1][lrow] = b4.y;
        Bs[lk + 2][lrow] = b4.z; Bs[lk + 3][lrow] = b4.w;
        __syncthreads();
#pragma unroll
        for (int kk = 0; kk < 16; kk++) {
            float av[4], bv[4];
#pragma unroll
            for (int i = 0; i < 4; i++) av[i] = As[kk][ty * 4 + i];
#pragma unroll
            for (int j = 0; j < 4; j++) bv[j] = Bs[kk][tx * 4 + j];
#pragma unroll
            for (int i = 0; i < 4; i++)
#pragma unroll
                for (int j = 0; j < 4; j++) acc[i][j] += av[i] * bv[j];
        }
    }
#pragma unroll
    for (int i = 0; i < 4; i++) {
        int r = bm + ty * 4 + i;
        if (r >= M) continue;
#pragma unroll
        for (int j = 0; j < 4; j++) {
            int c = bn + tx * 4 + j;
            C[(size_t)r * N + c] = acc[i][j] + bias[c];
        }
    }
}

// Multi-segment f32 -> bf16 convert (one launch for all weights).
struct CvtTable {
    const float* src[9];
    unsigned short* dst[9];
    int cum4[10];   // prefix sums in float4 units
};
__global__ void cvt_multi(CvtTable t, int total4) {
    int i = blockIdx.x * 256 + threadIdx.x;
    if (i >= total4) return;
    int k = 0;
#pragma unroll
    for (int j = 0; j < 8; j++) if (i >= t.cum4[j + 1]) k = j + 1;
    int o = i - t.cum4[k];
    float4 v = ((const float4*)t.src[k])[o];
    ushort4 u;
    u.x = f2bf(v.x); u.y = f2bf(v.y); u.z = f2bf(v.z); u.w = f2bf(v.w);
    ((ushort4*)t.dst[k])[o] = u;
}

// vwT[l][k][j] = vw[l][j][k], f32 -> bf16. grid (16,16,2), block (32,8).
__global__ void cvt_transpose512(const float* __restrict__ vw, unsigned short* __restrict__ vwT) {
    __shared__ float tile[32][33];
    int l = blockIdx.z;
    int j0 = blockIdx.y * 32, k0 = blockIdx.x * 32;
    const float* src = vw + (size_t)l * 512 * 512;
    for (int r = threadIdx.y; r < 32; r += 8)
        tile[r][threadIdx.x] = src[(size_t)(j0 + r) * 512 + k0 + threadIdx.x];
    __syncthreads();
    unsigned short* dst = vwT + (size_t)l * 512 * 512;
    for (int r = threadIdx.y; r < 32; r += 8)
        dst[(size_t)(k0 + r) * 512 + j0 + threadIdx.x] = f2bf(tile[threadIdx.x][r]);
}

// Small prep: z<2 -> bfuse[l*512+n] = ow[l][n]·vb[l] + ob[l][n]; z==2 -> concat kv bias.
// grid (512, 3), block 64.
__global__ void prep_small(const float* __restrict__ ow, const float* __restrict__ vb,
                           const float* __restrict__ ob, const float* __restrict__ kb,
                           const float* __restrict__ vb2, float* __restrict__ bfuse,
                           float* __restrict__ kvb) {
    int n = blockIdx.x, z = blockIdx.y, lane = threadIdx.x;
    if (z == 2) {
        if (lane == 0) { kvb[n] = kb[n]; kvb[n + 512] = vb2[n]; }
        return;
    }
    const float* owr = ow + (size_t)z * 512 * 512 + (size_t)n * 512;
    const float* vbr = vb + (size_t)z * 512;
    float s = 0.f;
#pragma unroll
    for (int j = 0; j < 8; j++) s += owr[lane + 64 * j] * vbr[lane + 64 * j];
#pragma unroll
    for (int off = 32; off; off >>= 1) s += __shfl_xor(s, off, 64);
    if (lane == 0) bfuse[z * 512 + n] = s + ob[z * 512 + n];
}

// Row L2 norms of proj. grid = R_, block 64.
__global__ void rnorm_kernel(const float* __restrict__ proj, float* __restrict__ rn) {
    int r = blockIdx.x, lane = threadIdx.x;
    const float* p = proj + (size_t)r * D_;
    float s = 0.f;
#pragma unroll
    for (int j = 0; j < 8; j++) { float v = p[lane + 64 * j]; s += v * v; }
#pragma unroll
    for (int off = 32; off; off >>= 1) s += __shfl_xor(s, off, 64);
    if (lane == 0) rn[r] = sqrtf(s);
}

// Per-edge cosine sims -> stable top-8 -> mean agg (bf16) + states init (f32).
__global__ void sim_topk_agg(const int* __restrict__ eids, const int* __restrict__ nids,
                             const float* __restrict__ proj, const float* __restrict__ rn,
                             unsigned short* __restrict__ agg_bf, float* __restrict__ states) {
    int be = blockIdx.x, tid = threadIdx.x;
    __shared__ float ev[512];
    __shared__ float sims[32];
    __shared__ int nid_s[32];
    __shared__ int sel[8];

    int eid = eids[be];
    const float* ep = proj + (size_t)eid * D_;
    float e0 = ep[tid], e1 = ep[tid + 256];
    ev[tid] = e0; ev[tid + 256] = e1;
    states[(size_t)be * D_ + tid] = e0;
    states[(size_t)be * D_ + tid + 256] = e1;
    if (tid < 32) nid_s[tid] = nids[be * N_ + tid];
    __syncthreads();

    int wid = tid >> 6, lane = tid & 63;
    float en = fmaxf(rn[eid], 1e-12f);
    for (int n = wid; n < N_; n += 4) {
        int nid = nid_s[n];
        const float* np = proj + (size_t)nid * D_;
        float s = 0.f;
#pragma unroll
        for (int j = 0; j < 8; j++) s += np[lane + 64 * j] * ev[lane + 64 * j];
#pragma unroll
        for (int off = 32; off; off >>= 1) s += __shfl_xor(s, off, 64);
        if (lane == 0) sims[n] = s / (fmaxf(rn[nid], 1e-12f) * en);
    }
    __syncthreads();

    if (tid == 0) {
        unsigned used = 0;
        for (int k = 0; k < K_; k++) {
            float best = -3.402823466e38f; int bi = 0;
            for (int n = 0; n < N_; n++)
                if (!((used >> n) & 1u) && sims[n] > best) { best = sims[n]; bi = n; }
            used |= 1u << bi;
            sel[k] = nid_s[bi];
        }
    }
    __syncthreads();

    float a0 = 0.f, a1 = 0.f;
#pragma unroll
    for (int k = 0; k < K_; k++) {
        const float* sp = proj + (size_t)sel[k] * D_;
        a0 += sp[tid]; a1 += sp[tid + 256];
    }
    agg_bf[(size_t)be * D_ + tid] = f2bf(a0 * 0.125f);
    agg_bf[(size_t)be * D_ + tid + 256] = f2bf(a1 * 0.125f);
}

// out = LN(x + y)*g + b (optional *mask); y has row stride ystride.
__global__ void add_ln_kernel(const float* __restrict__ x, const float* __restrict__ y,
                              int ystride, const float* __restrict__ g,
                              const float* __restrict__ bb, const float* __restrict__ mask,
                              float* __restrict__ out, unsigned short* __restrict__ out_bf) {
    int t = blockIdx.x, tid = threadIdx.x;
    const float* xr = x + (size_t)t * D_;
    const float* yr = y + (size_t)t * ystride;
    float x0 = xr[tid] + yr[tid];
    float x1 = xr[tid + 256] + yr[tid + 256];
    __shared__ float red[8];
    float s = x0 + x1;
#pragma unroll
    for (int off = 32; off; off >>= 1) s += __shfl_xor(s, off, 64);
    int wid = tid >> 6;
    if ((tid & 63) == 0) red[wid] = s;
    __syncthreads();
    float mean = (red[0] + red[1] + red[2] + red[3]) * (1.f / 512.f);
    float d0 = x0 - mean, d1 = x1 - mean;
    float v = d0 * d0 + d1 * d1;
#pragma unroll
    for (int off = 32; off; off >>= 1) v += __shfl_xor(v, off, 64);
    if ((tid & 63) == 0) red[4 + wid] = v;
    __syncthreads();
    float var = (red[4] + red[5] + red[6] + red[7]) * (1.f / 512.f);
    float rs = rsqrtf(var + 1e-5f);
    float mv = mask ? mask[t] : 1.f;
    float o0 = (d0 * rs * g[tid] + bb[tid]) * mv;
    float o1 = (d1 * rs * g[tid + 256] + bb[tid + 256]) * mv;
    out[(size_t)t * D_ + tid] = o0;
    out[(size_t)t * D_ + tid + 256] = o1;
    out_bf[(size_t)t * D_ + tid] = f2bf(o0);
    out_bf[(size_t)t * D_ + tid + 256] = f2bf(o1);
}

// Cross-attention over combined kv [T,1024] (k cols 0-511, v cols 512-1023).
// grid = B_*M_, block 256 (thread = edge). Writes bf16 memb.
__global__ void mem_attn(const float* __restrict__ qb, const float* __restrict__ kv,
                         const float* __restrict__ mask, unsigned short* __restrict__ memb) {
    int b = blockIdx.x >> 5;
    int m = blockIdx.x & 31;
    int tid = threadIdx.x;
    __shared__ float qh[64];
    __shared__ float sc[256];
    __shared__ float red[8];
    __shared__ float oacc[4][64];

    float mk = mask[b * E_ + tid];
    for (int h = 0; h < H_; h++) {
        if (tid < 64) qh[tid] = qb[m * D_ + h * DH_ + tid];
        __syncthreads();
        const float* kr = kv + ((size_t)(b * E_ + tid)) * 1024 + h * DH_;
        float s = 0.f;
#pragma unroll
        for (int d = 0; d < DH_; d += 4) {
            float4 k4 = *(const float4*)(kr + d);
            s += k4.x * qh[d] + k4.y * qh[d + 1] + k4.z * qh[d + 2] + k4.w * qh[d + 3];
        }
        s *= 0.125f;
        if (mk == 0.f) s = -3.402823466e38f;
        float mx = s;
#pragma unroll
        for (int off = 32; off; off >>= 1) mx = fmaxf(mx, __shfl_xor(mx, off, 64));
        if ((tid & 63) == 0) red[tid >> 6] = mx;
        __syncthreads();
        mx = fmaxf(fmaxf(red[0], red[1]), fmaxf(red[2], red[3]));
        float p = expf(s - mx);
        float sum = p;
#pragma unroll
        for (int off = 32; off; off >>= 1) sum += __shfl_xor(sum, off, 64);
        if ((tid & 63) == 0) red[4 + (tid >> 6)] = sum;
        __syncthreads();
        sum = red[4] + red[5] + red[6] + red[7];
        sc[tid] = p / sum;
        __syncthreads();
        int d = tid & 63, part = tid >> 6;
        const float* vcol = kv + ((size_t)(b * E_ + part * 64)) * 1024 + 512 + h * DH_ + d;
        float acc = 0.f;
#pragma unroll 8
        for (int e = 0; e < 64; e++) acc += sc[part * 64 + e] * vcol[(size_t)e * 1024];
        oacc[part][d] = acc;
        __syncthreads();
        if (part == 0)
            memb[((size_t)(b * M_ + m)) * D_ + h * DH_ + d] =
                f2bf(oacc[0][d] + oacc[1][d] + oacc[2][d] + oacc[3][d]);
        __syncthreads();
    }
}

// Zero bf16 mem rows of batches with zero edges. grid B_, block 256.
__global__ void mask_zero(const float* __restrict__ mask, unsigned short* __restrict__ mem2) {
    int b = blockIdx.x, tid = threadIdx.x;
    float s = mask[b * E_ + tid];
    __shared__ float red[4];
#pragma unroll
    for (int off = 32; off; off >>= 1) s += __shfl_xor(s, off, 64);
    if ((tid & 63) == 0) red[tid >> 6] = s;
    __syncthreads();
    if (red[0] + red[1] + red[2] + red[3] == 0.f) {
        for (int i = tid; i < M_ * D_; i += 256)
            mem2[(size_t)b * M_ * D_ + i] = 0;
    }
}

extern "C" void kernel_launch(void* const* d_in, const int* in_sizes, int n_in,
                              void* d_out, int out_size, void* d_ws, size_t ws_size,
                              hipStream_t stream) {
    const int*   edge_rel_ids     = (const int*)d_in[0];
    const int*   neighbor_rel_ids = (const int*)d_in[1];
    const float* edge_mask        = (const float*)d_in[2];
    const float* rel_emb          = (const float*)d_in[3];
    const float* rp_w             = (const float*)d_in[4];
    const float* rp_b             = (const float*)d_in[5];
    const float* ly_vw            = (const float*)d_in[6];
    const float* ly_vb            = (const float*)d_in[7];
    const float* ly_ow            = (const float*)d_in[8];
    const float* ly_ob            = (const float*)d_in[9];
    const float* ly_n1g           = (const float*)d_in[10];
    const float* ly_n1b           = (const float*)d_in[11];
    const float* ly_n2g           = (const float*)d_in[12];
    const float* ly_n2b           = (const float*)d_in[13];
    const float* ly_w1            = (const float*)d_in[14];
    const float* ly_b1            = (const float*)d_in[15];
    const float* ly_w2            = (const float*)d_in[16];
    const float* ly_b2            = (const float*)d_in[17];
    const float* mem_q            = (const float*)d_in[18];
    const float* t_qw             = (const float*)d_in[19];
    const float* t_qb             = (const float*)d_in[20];
    const float* t_kw             = (const float*)d_in[21];
    const float* t_kb             = (const float*)d_in[22];
    const float* t_vw             = (const float*)d_in[23];
    const float* t_vb             = (const float*)d_in[24];
    const float* t_ow             = (const float*)d_in[25];
    const float* t_ob             = (const float*)d_in[26];
    const float* proj_w           = (const float*)d_in[27];
    const float* proj_b           = (const float*)d_in[28];
    float* out = (float*)d_out;
    (void)ws_size; (void)in_sizes; (void)n_in; (void)out_size;

    char* ws = (char*)d_ws;
    size_t off = 0;
    auto allocf = [&](size_t n) { float* p = (float*)(ws + off); off += ((n * 4 + 255) & ~(size_t)255); return p; };
    auto allocb = [&](size_t n) { unsigned short* p = (unsigned short*)(ws + off); off += ((n * 2 + 255) & ~(size_t)255); return p; };

    const int T = B_ * E_;   // 2048

    // fp32 buffers
    float* proj    = allocf((size_t)R_ * D_);
    float* rn      = allocf(R_);
    float* states  = allocf((size_t)T * D_);
    float* tmpB    = allocf((size_t)T * D_);
    float* attnall = allocf((size_t)T * 2 * D_);   // [2048,1024]; reused as kvbuf
    float* qbuf    = allocf((size_t)M_ * D_);
    float* bfuse   = allocf(2 * D_);
    float* kvb     = allocf(2 * D_);
    float* kvbuf   = attnall;                       // alias: attnall dead after layers

    // bf16 buffers
    unsigned short* rel_bf    = allocb((size_t)2048 * RD_);   // padded rows for unguarded loads
    unsigned short* rpw_bf    = allocb((size_t)D_ * RD_);
    unsigned short* agg_bf    = allocb((size_t)T * D_);
    unsigned short* states_bf = allocb((size_t)T * D_);
    unsigned short* ff1_bf    = allocb((size_t)T * 4 * D_);
    unsigned short* vwT_bf    = allocb((size_t)L_ * D_ * D_);
    unsigned short* ow_bf     = allocb((size_t)L_ * D_ * D_);
    unsigned short* wfuse_bf  = allocb((size_t)L_ * D_ * D_);
    unsigned short* w1_bf     = allocb((size_t)L_ * 4 * D_ * D_);
    unsigned short* w2_bf     = allocb((size_t)L_ * 4 * D_ * D_);
    unsigned short* kvw_bf    = allocb((size_t)2 * D_ * D_);
    unsigned short* tow_bf    = allocb((size_t)D_ * D_);
    unsigned short* pw_bf     = allocb((size_t)HL_ * D_);
    unsigned short* memb_bf   = allocb((size_t)B_ * M_ * D_);
    unsigned short* mem2_bf   = allocb((size_t)B_ * M_ * D_);

    // 0a. all straight f32->bf16 weight conversions in ONE kernel
    CvtTable t;
    int sizes[9] = { R_ * RD_, D_ * RD_, L_ * D_ * D_, L_ * 4 * D_ * D_,
                     L_ * 4 * D_ * D_, D_ * D_, D_ * D_, D_ * D_, HL_ * D_ };
    const float* srcs[9] = { rel_emb, rp_w, ly_ow, ly_w1, ly_w2, t_kw, t_vw, t_ow, proj_w };
    unsigned short* dsts[9] = { rel_bf, rpw_bf, ow_bf, w1_bf, w2_bf,
                                kvw_bf, kvw_bf + (size_t)D_ * D_, tow_bf, pw_bf };
    int cum = 0;
    for (int i = 0; i < 9; i++) {
        t.src[i] = srcs[i]; t.dst[i] = dsts[i];
        t.cum4[i] = cum; cum += sizes[i] / 4;
    }
    t.cum4[9] = cum;
    cvt_multi<<<(cum + 255) / 256, 256, 0, stream>>>(t, cum);
    // 0b. vw transposed convert (for the Wfuse GEMM)
    cvt_transpose512<<<dim3(16, 16, 2), dim3(32, 8), 0, stream>>>(ly_vw, vwT_bf);
    // 0c. fused biases + concat kv bias
    prep_small<<<dim3(512, 3), 64, 0, stream>>>(ly_ow, ly_vb, ly_ob, t_kb, t_vb, bfuse, kvb);

    // 1. proj = rel_emb @ rp_w^T + rp_b  (bf16 MFMA, f32 out; M=2000 store-guarded)
    gemm_mfma<64, 64, 0, 0, 1><<<dim3(D_ / 64, 32), 256, 0, stream>>>(
        rel_bf, rpw_bf, rp_b, proj, R_, D_, RD_);
    // 2. norms
    rnorm_kernel<<<R_, 64, 0, stream>>>(proj, rn);
    // 3. sims + top-k + aggregate + states init
    sim_topk_agg<<<T, 256, 0, stream>>>(edge_rel_ids, neighbor_rel_ids, proj, rn,
                                        agg_bf, states);

    // 4a. Wfuse_l = ow_l @ vw_l  (bf16 out), both layers
    for (int l = 0; l < L_; l++)
        gemm_mfma<64, 64, 0, 1, 0><<<dim3(8, 8), 256, 0, stream>>>(
            ow_bf + (size_t)l * D_ * D_, vwT_bf + (size_t)l * D_ * D_, nullptr,
            wfuse_bf + (size_t)l * D_ * D_, D_, D_, D_);
    // 4b. attn (both layers) = agg @ Wfuse^T + bfuse   [2048, 1024]
    gemm_mfma<64, 64, 0, 0, 1><<<dim3(2 * D_ / 64, T / 64), 256, 0, stream>>>(
        agg_bf, wfuse_bf, bfuse, attnall, T, 2 * D_, D_);

    // 4c. layer stack
    for (int l = 0; l < L_; l++) {
        add_ln_kernel<<<T, 256, 0, stream>>>(states, attnall + (size_t)l * D_, 2 * D_,
                                             ly_n1g + l * D_, ly_n1b + l * D_, nullptr,
                                             states, states_bf);
        gemm_mfma<128, 128, 1, 1, 1><<<dim3(4 * D_ / 128, T / 128), 256, 0, stream>>>(
            states_bf, w1_bf + (size_t)l * 4 * D_ * D_, ly_b1 + l * 4 * D_,
            ff1_bf, T, 4 * D_, D_);
        gemm_mfma<64, 64, 0, 0, 1><<<dim3(D_ / 64, T / 64), 256, 0, stream>>>(
            ff1_bf, w2_bf + (size_t)l * 4 * D_ * D_, ly_b2 + l * D_,
            tmpB, T, D_, 4 * D_);
        add_ln_kernel<<<T, 256, 0, stream>>>(states, tmpB, D_,
                                             ly_n2g + l * D_, ly_n2b + l * D_, edge_mask,
                                             states, states_bf);
    }

    // 5. combined k|v projection -> kvbuf [2048, 1024] (aliases attnall — attnall dead)
    gemm_mfma<64, 64, 0, 0, 1><<<dim3(2 * D_ / 64, T / 64), 256, 0, stream>>>(
        states_bf, kvw_bf, kvb, kvbuf, T, 2 * D_, D_);
    // q projection (tiny, exact fp32)
    gemm_nt<<<dim3(D_ / 64, 1), 256, 0, stream>>>(mem_q, t_qw, t_qb, qbuf, M_, D_, D_);

    // 6. memory cross-attention -> memb (bf16)
    mem_attn<<<B_ * M_, 256, 0, stream>>>(qbuf, kvbuf, edge_mask, memb_bf);

    // 7. out-proj of attention (bf16 MFMA) + no-edge zeroing
    gemm_mfma<64, 64, 0, 1, 1><<<dim3(D_ / 64, 4), 256, 0, stream>>>(
        memb_bf, tow_bf, t_ob, mem2_bf, B_ * M_, D_, D_);
    mask_zero<<<B_, 256, 0, stream>>>(edge_mask, mem2_bf);

    // 8. final LLM projection (bf16 MFMA, f32 out)
    gemm_mfma<64, 64, 0, 0, 1><<<dim3(HL_ / 64, 4), 256, 0, stream>>>(
        mem2_bf, pw_bf, proj_b, out, B_ * M_, HL_, D_);
}

// Round 6
// 396.038 us; speedup vs baseline: 2.7034x; 1.1626x over previous
//
#include <hip/hip_runtime.h>
#include <hip/hip_bf16.h>
#include <math.h>

#define B_   8
#define E_   256
#define N_   32
#define D_   512
#define RD_  768
#define R_   2000
#define L_   2
#define K_   8
#define M_   32
#define H_   8
#define DH_  64
#define HL_  4096

typedef float f32x4 __attribute__((ext_vector_type(4)));
typedef __bf16 bf16x8 __attribute__((ext_vector_type(8)));
typedef const __attribute__((address_space(1))) void GVoid;
typedef __attribute__((address_space(3))) void LVoid;

__device__ __forceinline__ float gelu_exact(float x) {
    return 0.5f * x * (1.0f + erff(x * 0.70710678118654752f));
}
__device__ __forceinline__ unsigned short f2bf(float x) {
    return __hip_bfloat16_raw(__float2bfloat16(x)).x;
}

// ---------------------------------------------------------------------------
// bf16 MFMA GEMM, m97-style: C[M,N] = A[M,K](bf16) @ W[N,K](bf16)^T [+bias].
// BK=64. Staging via global_load_lds width=16 (async, no VGPR round-trip).
// LDS layout: row-major, row stride 64 hw (128 B) split into 8 16-B chunks;
// chunk c of row r stored at chunk index c^(r&7)  (XOR swizzle -> 2-way max
// ds_read_b128 conflicts, and compatible with global_load_lds's fixed
// "uniform base + lane*16" scatter: lane supplies the matching global chunk).
// 256 threads, 2x2 wave grid, each wave (TM/2)x(TN/2). Requires TM in
// {32,64}, N%TN==0, K%64==0, A rows allocated up to ceil(M/TM)*TM.
// Store guarded by r<M.
// ---------------------------------------------------------------------------
template <int TM, int TN, int ACT_GELU, int OUT_BF16, int HAS_BIAS>
__global__ __launch_bounds__(256) void gemm_mfma(const unsigned short* __restrict__ A,
                                                 const unsigned short* __restrict__ W,
                                                 const float* __restrict__ bias,
                                                 void* __restrict__ Cv,
                                                 int M, int N, int K) {
    constexpr int WTM = TM / 2, WTN = TN / 2;
    constexpr int RM = WTM / 16, RN = WTN / 16;
    constexpr int AI = TM / 32;   // global_load_lds insts per wave for A tile
    constexpr int BI = TN / 32;
    __shared__ __align__(16) unsigned short As[TM * 64];
    __shared__ __align__(16) unsigned short Bs[TN * 64];

    const int tid = threadIdx.x;
    const int wave = tid >> 6, lane = tid & 63;
    const int quad = lane >> 4, l16 = lane & 15;
    const int wm = wave >> 1, wn = wave & 1;
    const int bm = blockIdx.y * TM, bn = blockIdx.x * TN;

    // staging geometry: instruction writes 64 chunks = 8 rows; lane l covers
    // row r0+(l>>3), chunk slot l&7, which must hold global chunk (l&7)^(r&7).
    const int sub = lane >> 3;            // r & 7 for this lane
    const int cpr = (lane & 7) ^ sub;     // global chunk this lane fetches

    f32x4 acc[RM][RN];
#pragma unroll
    for (int i = 0; i < RM; i++)
#pragma unroll
        for (int j = 0; j < RN; j++) acc[i][j] = (f32x4){0.f, 0.f, 0.f, 0.f};

    for (int k0 = 0; k0 < K; k0 += 64) {
        __syncthreads();
#pragma unroll
        for (int i = 0; i < AI; i++) {
            int r0 = (wave * AI + i) * 8;
            const unsigned short* g = A + (size_t)(bm + r0 + sub) * K + k0 + cpr * 8;
            __builtin_amdgcn_global_load_lds((GVoid*)g, (LVoid*)&As[r0 * 64], 16, 0, 0);
        }
#pragma unroll
        for (int i = 0; i < BI; i++) {
            int r0 = (wave * BI + i) * 8;
            const unsigned short* g = W + (size_t)(bn + r0 + sub) * K + k0 + cpr * 8;
            __builtin_amdgcn_global_load_lds((GVoid*)g, (LVoid*)&Bs[r0 * 64], 16, 0, 0);
        }
        __syncthreads();   // compiler drains vmcnt before barrier

#pragma unroll
        for (int h = 0; h < 2; h++) {
            bf16x8 af[RM], bf[RN];
#pragma unroll
            for (int i = 0; i < RM; i++) {
                int r = wm * WTM + i * 16 + l16;
                int ch = (h * 4 + quad) ^ (r & 7);
                af[i] = *(const bf16x8*)&As[r * 64 + ch * 8];
            }
#pragma unroll
            for (int j = 0; j < RN; j++) {
                int r = wn * WTN + j * 16 + l16;
                int ch = (h * 4 + quad) ^ (r & 7);
                bf[j] = *(const bf16x8*)&Bs[r * 64 + ch * 8];
            }
#pragma unroll
            for (int i = 0; i < RM; i++)
#pragma unroll
                for (int j = 0; j < RN; j++)
                    acc[i][j] = __builtin_amdgcn_mfma_f32_16x16x32_bf16(af[i], bf[j], acc[i][j], 0, 0, 0);
        }
    }

#pragma unroll
    for (int i = 0; i < RM; i++) {
#pragma unroll
        for (int j = 0; j < RN; j++) {
            int c = bn + wn * WTN + j * 16 + l16;
            float bv = HAS_BIAS ? bias[c] : 0.f;
#pragma unroll
            for (int reg = 0; reg < 4; reg++) {
                int r = bm + wm * WTM + i * 16 + quad * 4 + reg;
                if (r < M) {
                    float v = acc[i][j][reg] + bv;
                    if (ACT_GELU) v = gelu_exact(v);
                    if (OUT_BF16)
                        ((unsigned short*)Cv)[(size_t)r * N + c] = f2bf(v);
                    else
                        ((float*)Cv)[(size_t)r * N + c] = v;
                }
            }
        }
    }
}

// fp32 GEMM (tiny q-proj only): C = A @ B^T + bias. 64x64 tile.
__global__ void gemm_nt(const float* __restrict__ A, const float* __restrict__ Bm,
                        const float* __restrict__ bias, float* __restrict__ C,
                        int M, int N, int K) {
    __shared__ float As[16][65];
    __shared__ float Bs[16][65];
    const int tid = threadIdx.x;
    const int bm = blockIdx.y * 64, bn = blockIdx.x * 64;
    const int tx = tid & 15, ty = tid >> 4;
    const int lrow = tid >> 2, lk = (tid & 3) << 2;
    float acc[4][4] = {{0.f}};
    const int arow = bm + lrow, brow = bn + lrow;
    for (int k0 = 0; k0 < K; k0 += 16) {
        float4 a4 = make_float4(0.f, 0.f, 0.f, 0.f);
        if (arow < M) a4 = *(const float4*)(A + (size_t)arow * K + k0 + lk);
        float4 b4 = *(const float4*)(Bm + (size_t)brow * K + k0 + lk);
        __syncthreads();
        As[lk + 0][lrow] = a4.x; As[lk + 1][lrow] = a4.y;
        As[lk + 2][lrow] = a4.z; As[lk + 3][lrow] = a4.w;
        Bs[lk + 0][lrow] = b4.x; Bs[lk + 1][lrow] = b4.y;
        Bs[lk + 2][lrow] = b4.z; Bs[lk + 3][lrow] = b4.w;
        __syncthreads();
#pragma unroll
        for (int kk = 0; kk < 16; kk++) {
            float av[4], bv[4];
#pragma unroll
            for (int i = 0; i < 4; i++) av[i] = As[kk][ty * 4 + i];
#pragma unroll
            for (int j = 0; j < 4; j++) bv[j] = Bs[kk][tx * 4 + j];
#pragma unroll
            for (int i = 0; i < 4; i++)
#pragma unroll
                for (int j = 0; j < 4; j++) acc[i][j] += av[i] * bv[j];
        }
    }
#pragma unroll
    for (int i = 0; i < 4; i++) {
        int r = bm + ty * 4 + i;
        if (r >= M) continue;
#pragma unroll
        for (int j = 0; j < 4; j++) {
            int c = bn + tx * 4 + j;
            C[(size_t)r * N + c] = acc[i][j] + bias[c];
        }
    }
}

// Multi-segment f32 -> bf16 convert (one launch for all weights).
struct CvtTable {
    const float* src[9];
    unsigned short* dst[9];
    int cum4[10];
};
__global__ void cvt_multi(CvtTable t, int total4) {
    int i = blockIdx.x * 256 + threadIdx.x;
    if (i >= total4) return;
    int k = 0;
#pragma unroll
    for (int j = 0; j < 8; j++) if (i >= t.cum4[j + 1]) k = j + 1;
    int o = i - t.cum4[k];
    float4 v = ((const float4*)t.src[k])[o];
    ushort4 u;
    u.x = f2bf(v.x); u.y = f2bf(v.y); u.z = f2bf(v.z); u.w = f2bf(v.w);
    ((ushort4*)t.dst[k])[o] = u;
}

// vwT[l][k][j] = vw[l][j][k], f32 -> bf16. grid (16,16,2), block (32,8).
__global__ void cvt_transpose512(const float* __restrict__ vw, unsigned short* __restrict__ vwT) {
    __shared__ float tile[32][33];
    int l = blockIdx.z;
    int j0 = blockIdx.y * 32, k0 = blockIdx.x * 32;
    const float* src = vw + (size_t)l * 512 * 512;
    for (int r = threadIdx.y; r < 32; r += 8)
        tile[r][threadIdx.x] = src[(size_t)(j0 + r) * 512 + k0 + threadIdx.x];
    __syncthreads();
    unsigned short* dst = vwT + (size_t)l * 512 * 512;
    for (int r = threadIdx.y; r < 32; r += 8)
        dst[(size_t)(k0 + r) * 512 + j0 + threadIdx.x] = f2bf(tile[threadIdx.x][r]);
}

// z<2: bfuse[z*512+n] = ow[z][n]·vb[z] + ob[z][n]; z==2: concat kv bias.
__global__ void prep_small(const float* __restrict__ ow, const float* __restrict__ vb,
                           const float* __restrict__ ob, const float* __restrict__ kb,
                           const float* __restrict__ vb2, float* __restrict__ bfuse,
                           float* __restrict__ kvb) {
    int n = blockIdx.x, z = blockIdx.y, lane = threadIdx.x;
    if (z == 2) {
        if (lane == 0) { kvb[n] = kb[n]; kvb[n + 512] = vb2[n]; }
        return;
    }
    const float* owr = ow + (size_t)z * 512 * 512 + (size_t)n * 512;
    const float* vbr = vb + (size_t)z * 512;
    float s = 0.f;
#pragma unroll
    for (int j = 0; j < 8; j++) s += owr[lane + 64 * j] * vbr[lane + 64 * j];
#pragma unroll
    for (int off = 32; off; off >>= 1) s += __shfl_xor(s, off, 64);
    if (lane == 0) bfuse[z * 512 + n] = s + ob[z * 512 + n];
}

// Row L2 norms of proj. grid = R_, block 64.
__global__ void rnorm_kernel(const float* __restrict__ proj, float* __restrict__ rn) {
    int r = blockIdx.x, lane = threadIdx.x;
    const float* p = proj + (size_t)r * D_;
    float s = 0.f;
#pragma unroll
    for (int j = 0; j < 8; j++) { float v = p[lane + 64 * j]; s += v * v; }
#pragma unroll
    for (int off = 32; off; off >>= 1) s += __shfl_xor(s, off, 64);
    if (lane == 0) rn[r] = sqrtf(s);
}

// Per-edge cosine sims -> stable top-8 -> mean agg (bf16) + states init (f32).
__global__ void sim_topk_agg(const int* __restrict__ eids, const int* __restrict__ nids,
                             const float* __restrict__ proj, const float* __restrict__ rn,
                             unsigned short* __restrict__ agg_bf, float* __restrict__ states) {
    int be = blockIdx.x, tid = threadIdx.x;
    __shared__ float ev[512];
    __shared__ float sims[32];
    __shared__ int nid_s[32];
    __shared__ int sel[8];

    int eid = eids[be];
    const float* ep = proj + (size_t)eid * D_;
    float e0 = ep[tid], e1 = ep[tid + 256];
    ev[tid] = e0; ev[tid + 256] = e1;
    states[(size_t)be * D_ + tid] = e0;
    states[(size_t)be * D_ + tid + 256] = e1;
    if (tid < 32) nid_s[tid] = nids[be * N_ + tid];
    __syncthreads();

    int wid = tid >> 6, lane = tid & 63;
    float en = fmaxf(rn[eid], 1e-12f);
    for (int n = wid; n < N_; n += 4) {
        int nid = nid_s[n];
        const float* np = proj + (size_t)nid * D_;
        float s = 0.f;
#pragma unroll
        for (int j = 0; j < 8; j++) s += np[lane + 64 * j] * ev[lane + 64 * j];
#pragma unroll
        for (int off = 32; off; off >>= 1) s += __shfl_xor(s, off, 64);
        if (lane == 0) sims[n] = s / (fmaxf(rn[nid], 1e-12f) * en);
    }
    __syncthreads();

    if (tid == 0) {
        unsigned used = 0;
        for (int k = 0; k < K_; k++) {
            float best = -3.402823466e38f; int bi = 0;
            for (int n = 0; n < N_; n++)
                if (!((used >> n) & 1u) && sims[n] > best) { best = sims[n]; bi = n; }
            used |= 1u << bi;
            sel[k] = nid_s[bi];
        }
    }
    __syncthreads();

    float a0 = 0.f, a1 = 0.f;
#pragma unroll
    for (int k = 0; k < K_; k++) {
        const float* sp = proj + (size_t)sel[k] * D_;
        a0 += sp[tid]; a1 += sp[tid + 256];
    }
    agg_bf[(size_t)be * D_ + tid] = f2bf(a0 * 0.125f);
    agg_bf[(size_t)be * D_ + tid + 256] = f2bf(a1 * 0.125f);
}

// out = LN(x + y)*g + b (optional *mask); y has row stride ystride.
__global__ void add_ln_kernel(const float* __restrict__ x, const float* __restrict__ y,
                              int ystride, const float* __restrict__ g,
                              const float* __restrict__ bb, const float* __restrict__ mask,
                              float* __restrict__ out, unsigned short* __restrict__ out_bf) {
    int t = blockIdx.x, tid = threadIdx.x;
    const float* xr = x + (size_t)t * D_;
    const float* yr = y + (size_t)t * ystride;
    float x0 = xr[tid] + yr[tid];
    float x1 = xr[tid + 256] + yr[tid + 256];
    __shared__ float red[8];
    float s = x0 + x1;
#pragma unroll
    for (int off = 32; off; off >>= 1) s += __shfl_xor(s, off, 64);
    int wid = tid >> 6;
    if ((tid & 63) == 0) red[wid] = s;
    __syncthreads();
    float mean = (red[0] + red[1] + red[2] + red[3]) * (1.f / 512.f);
    float d0 = x0 - mean, d1 = x1 - mean;
    float v = d0 * d0 + d1 * d1;
#pragma unroll
    for (int off = 32; off; off >>= 1) v += __shfl_xor(v, off, 64);
    if ((tid & 63) == 0) red[4 + wid] = v;
    __syncthreads();
    float var = (red[4] + red[5] + red[6] + red[7]) * (1.f / 512.f);
    float rs = rsqrtf(var + 1e-5f);
    float mv = mask ? mask[t] : 1.f;
    float o0 = (d0 * rs * g[tid] + bb[tid]) * mv;
    float o1 = (d1 * rs * g[tid + 256] + bb[tid + 256]) * mv;
    out[(size_t)t * D_ + tid] = o0;
    out[(size_t)t * D_ + tid + 256] = o1;
    out_bf[(size_t)t * D_ + tid] = f2bf(o0);
    out_bf[(size_t)t * D_ + tid + 256] = f2bf(o1);
}

// Cross-attention over combined kv [T,1024]. grid = B_*M_, block 256.
__global__ void mem_attn(const float* __restrict__ qb, const float* __restrict__ kv,
                         const float* __restrict__ mask, unsigned short* __restrict__ memb) {
    int b = blockIdx.x >> 5;
    int m = blockIdx.x & 31;
    int tid = threadIdx.x;
    __shared__ float qh[64];
    __shared__ float sc[256];
    __shared__ float red[8];
    __shared__ float oacc[4][64];

    float mk = mask[b * E_ + tid];
    for (int h = 0; h < H_; h++) {
        if (tid < 64) qh[tid] = qb[m * D_ + h * DH_ + tid];
        __syncthreads();
        const float* kr = kv + ((size_t)(b * E_ + tid)) * 1024 + h * DH_;
        float s = 0.f;
#pragma unroll
        for (int d = 0; d < DH_; d += 4) {
            float4 k4 = *(const float4*)(kr + d);
            s += k4.x * qh[d] + k4.y * qh[d + 1] + k4.z * qh[d + 2] + k4.w * qh[d + 3];
        }
        s *= 0.125f;
        if (mk == 0.f) s = -3.402823466e38f;
        float mx = s;
#pragma unroll
        for (int off = 32; off; off >>= 1) mx = fmaxf(mx, __shfl_xor(mx, off, 64));
        if ((tid & 63) == 0) red[tid >> 6] = mx;
        __syncthreads();
        mx = fmaxf(fmaxf(red[0], red[1]), fmaxf(red[2], red[3]));
        float p = expf(s - mx);
        float sum = p;
#pragma unroll
        for (int off = 32; off; off >>= 1) sum += __shfl_xor(sum, off, 64);
        if ((tid & 63) == 0) red[4 + (tid >> 6)] = sum;
        __syncthreads();
        sum = red[4] + red[5] + red[6] + red[7];
        sc[tid] = p / sum;
        __syncthreads();
        int d = tid & 63, part = tid >> 6;
        const float* vcol = kv + ((size_t)(b * E_ + part * 64)) * 1024 + 512 + h * DH_ + d;
        float acc = 0.f;
#pragma unroll 8
        for (int e = 0; e < 64; e++) acc += sc[part * 64 + e] * vcol[(size_t)e * 1024];
        oacc[part][d] = acc;
        __syncthreads();
        if (part == 0)
            memb[((size_t)(b * M_ + m)) * D_ + h * DH_ + d] =
                f2bf(oacc[0][d] + oacc[1][d] + oacc[2][d] + oacc[3][d]);
        __syncthreads();
    }
}

// Zero bf16 mem rows of batches with zero edges. grid B_, block 256.
__global__ void mask_zero(const float* __restrict__ mask, unsigned short* __restrict__ mem2) {
    int b = blockIdx.x, tid = threadIdx.x;
    float s = mask[b * E_ + tid];
    __shared__ float red[4];
#pragma unroll
    for (int off = 32; off; off >>= 1) s += __shfl_xor(s, off, 64);
    if ((tid & 63) == 0) red[tid >> 6] = s;
    __syncthreads();
    if (red[0] + red[1] + red[2] + red[3] == 0.f) {
        for (int i = tid; i < M_ * D_; i += 256)
            mem2[(size_t)b * M_ * D_ + i] = 0;
    }
}

extern "C" void kernel_launch(void* const* d_in, const int* in_sizes, int n_in,
                              void* d_out, int out_size, void* d_ws, size_t ws_size,
                              hipStream_t stream) {
    const int*   edge_rel_ids     = (const int*)d_in[0];
    const int*   neighbor_rel_ids = (const int*)d_in[1];
    const float* edge_mask        = (const float*)d_in[2];
    const float* rel_emb          = (const float*)d_in[3];
    const float* rp_w             = (const float*)d_in[4];
    const float* rp_b             = (const float*)d_in[5];
    const float* ly_vw            = (const float*)d_in[6];
    const float* ly_vb            = (const float*)d_in[7];
    const float* ly_ow            = (const float*)d_in[8];
    const float* ly_ob            = (const float*)d_in[9];
    const float* ly_n1g           = (const float*)d_in[10];
    const float* ly_n1b           = (const float*)d_in[11];
    const float* ly_n2g           = (const float*)d_in[12];
    const float* ly_n2b           = (const float*)d_in[13];
    const float* ly_w1            = (const float*)d_in[14];
    const float* ly_b1            = (const float*)d_in[15];
    const float* ly_w2            = (const float*)d_in[16];
    const float* ly_b2            = (const float*)d_in[17];
    const float* mem_q            = (const float*)d_in[18];
    const float* t_qw             = (const float*)d_in[19];
    const float* t_qb             = (const float*)d_in[20];
    const float* t_kw             = (const float*)d_in[21];
    const float* t_kb             = (const float*)d_in[22];
    const float* t_vw             = (const float*)d_in[23];
    const float* t_vb             = (const float*)d_in[24];
    const float* t_ow             = (const float*)d_in[25];
    const float* t_ob             = (const float*)d_in[26];
    const float* proj_w           = (const float*)d_in[27];
    const float* proj_b           = (const float*)d_in[28];
    float* out = (float*)d_out;
    (void)ws_size; (void)in_sizes; (void)n_in; (void)out_size;

    char* ws = (char*)d_ws;
    size_t off = 0;
    auto allocf = [&](size_t n) { float* p = (float*)(ws + off); off += ((n * 4 + 255) & ~(size_t)255); return p; };
    auto allocb = [&](size_t n) { unsigned short* p = (unsigned short*)(ws + off); off += ((n * 2 + 255) & ~(size_t)255); return p; };

    const int T = B_ * E_;   // 2048

    float* proj    = allocf((size_t)R_ * D_);
    float* rn      = allocf(R_);
    float* states  = allocf((size_t)T * D_);
    float* tmpB    = allocf((size_t)T * D_);
    float* attnall = allocf((size_t)T * 2 * D_);
    float* qbuf    = allocf((size_t)M_ * D_);
    float* bfuse   = allocf(2 * D_);
    float* kvb     = allocf(2 * D_);
    float* kvbuf   = attnall;   // alias: attnall dead after layer stack

    unsigned short* rel_bf    = allocb((size_t)2048 * RD_);   // padded rows
    unsigned short* rpw_bf    = allocb((size_t)D_ * RD_);
    unsigned short* agg_bf    = allocb((size_t)T * D_);
    unsigned short* states_bf = allocb((size_t)T * D_);
    unsigned short* ff1_bf    = allocb((size_t)T * 4 * D_);
    unsigned short* vwT_bf    = allocb((size_t)L_ * D_ * D_);
    unsigned short* ow_bf     = allocb((size_t)L_ * D_ * D_);
    unsigned short* wfuse_bf  = allocb((size_t)L_ * D_ * D_);
    unsigned short* w1_bf     = allocb((size_t)L_ * 4 * D_ * D_);
    unsigned short* w2_bf     = allocb((size_t)L_ * 4 * D_ * D_);
    unsigned short* kvw_bf    = allocb((size_t)2 * D_ * D_);
    unsigned short* tow_bf    = allocb((size_t)D_ * D_);
    unsigned short* pw_bf     = allocb((size_t)HL_ * D_);
    unsigned short* memb_bf   = allocb((size_t)B_ * M_ * D_);
    unsigned short* mem2_bf   = allocb((size_t)B_ * M_ * D_);

    // 0a. straight f32->bf16 conversions in one kernel
    CvtTable t;
    int sizes[9] = { R_ * RD_, D_ * RD_, L_ * D_ * D_, L_ * 4 * D_ * D_,
                     L_ * 4 * D_ * D_, D_ * D_, D_ * D_, D_ * D_, HL_ * D_ };
    const float* srcs[9] = { rel_emb, rp_w, ly_ow, ly_w1, ly_w2, t_kw, t_vw, t_ow, proj_w };
    unsigned short* dsts[9] = { rel_bf, rpw_bf, ow_bf, w1_bf, w2_bf,
                                kvw_bf, kvw_bf + (size_t)D_ * D_, tow_bf, pw_bf };
    int cum = 0;
    for (int i = 0; i < 9; i++) {
        t.src[i] = srcs[i]; t.dst[i] = dsts[i];
        t.cum4[i] = cum; cum += sizes[i] / 4;
    }
    t.cum4[9] = cum;
    cvt_multi<<<(cum + 255) / 256, 256, 0, stream>>>(t, cum);
    // 0b. vw transposed convert
    cvt_transpose512<<<dim3(16, 16, 2), dim3(32, 8), 0, stream>>>(ly_vw, vwT_bf);
    // 0c. fused biases
    prep_small<<<dim3(512, 3), 64, 0, stream>>>(ly_ow, ly_vb, ly_ob, t_kb, t_vb, bfuse, kvb);

    // 1. proj = rel_emb @ rp_w^T + rp_b  (TM=32 -> 512 blocks)
    gemm_mfma<32, 64, 0, 0, 1><<<dim3(D_ / 64, 64), 256, 0, stream>>>(
        rel_bf, rpw_bf, rp_b, proj, R_, D_, RD_);
    // 2. norms
    rnorm_kernel<<<R_, 64, 0, stream>>>(proj, rn);
    // 3. sims + top-k + aggregate + states init
    sim_topk_agg<<<T, 256, 0, stream>>>(edge_rel_ids, neighbor_rel_ids, proj, rn,
                                        agg_bf, states);

    // 4a. Wfuse_l = ow_l @ vw_l (bf16 out)
    for (int l = 0; l < L_; l++)
        gemm_mfma<32, 64, 0, 1, 0><<<dim3(8, 16), 256, 0, stream>>>(
            ow_bf + (size_t)l * D_ * D_, vwT_bf + (size_t)l * D_ * D_, nullptr,
            wfuse_bf + (size_t)l * D_ * D_, D_, D_, D_);
    // 4b. attn (both layers) = agg @ Wfuse^T + bfuse  [2048,1024], 512 blocks
    gemm_mfma<64, 64, 0, 0, 1><<<dim3(2 * D_ / 64, T / 64), 256, 0, stream>>>(
        agg_bf, wfuse_bf, bfuse, attnall, T, 2 * D_, D_);

    // 4c. layer stack
    for (int l = 0; l < L_; l++) {
        add_ln_kernel<<<T, 256, 0, stream>>>(states, attnall + (size_t)l * D_, 2 * D_,
                                             ly_n1g + l * D_, ly_n1b + l * D_, nullptr,
                                             states, states_bf);
        // ff1: [2048,2048,512] -> 1024 blocks
        gemm_mfma<64, 64, 1, 1, 1><<<dim3(4 * D_ / 64, T / 64), 256, 0, stream>>>(
            states_bf, w1_bf + (size_t)l * 4 * D_ * D_, ly_b1 + l * 4 * D_,
            ff1_bf, T, 4 * D_, D_);
        // ff2: [2048,512,2048] -> TM=32, 512 blocks
        gemm_mfma<32, 64, 0, 0, 1><<<dim3(D_ / 64, T / 32), 256, 0, stream>>>(
            ff1_bf, w2_bf + (size_t)l * 4 * D_ * D_, ly_b2 + l * D_,
            tmpB, T, D_, 4 * D_);
        add_ln_kernel<<<T, 256, 0, stream>>>(states, tmpB, D_,
                                             ly_n2g + l * D_, ly_n2b + l * D_, edge_mask,
                                             states, states_bf);
    }

    // 5. combined k|v projection -> kvbuf [2048,1024], 512 blocks
    gemm_mfma<64, 64, 0, 0, 1><<<dim3(2 * D_ / 64, T / 64), 256, 0, stream>>>(
        states_bf, kvw_bf, kvb, kvbuf, T, 2 * D_, D_);
    // q projection (tiny, exact fp32)
    gemm_nt<<<dim3(D_ / 64, 1), 256, 0, stream>>>(mem_q, t_qw, t_qb, qbuf, M_, D_, D_);

    // 6. memory cross-attention -> memb (bf16)
    mem_attn<<<B_ * M_, 256, 0, stream>>>(qbuf, kvbuf, edge_mask, memb_bf);

    // 7. out-proj of attention + no-edge zeroing
    gemm_mfma<32, 64, 0, 1, 1><<<dim3(D_ / 64, 8), 256, 0, stream>>>(
        memb_bf, tow_bf, t_ob, mem2_bf, B_ * M_, D_, D_);
    mask_zero<<<B_, 256, 0, stream>>>(edge_mask, mem2_bf);

    // 8. final LLM projection [256,4096,512] -> TM=32, 512 blocks
    gemm_mfma<32, 64, 0, 0, 1><<<dim3(HL_ / 64, 8), 256, 0, stream>>>(
        mem2_bf, pw_bf, proj_b, out, B_ * M_, HL_, D_);
}

// Round 7
// 361.890 us; speedup vs baseline: 2.9585x; 1.0944x over previous
//
#include <hip/hip_runtime.h>
#include <hip/hip_bf16.h>
#include <math.h>

#define B_   8
#define E_   256
#define N_   32
#define D_   512
#define RD_  768
#define R_   2000
#define L_   2
#define K_   8
#define M_   32
#define H_   8
#define DH_  64
#define HL_  4096

typedef float f32x4 __attribute__((ext_vector_type(4)));
typedef __bf16 bf16x8 __attribute__((ext_vector_type(8)));
typedef const __attribute__((address_space(1))) void GVoid;
typedef __attribute__((address_space(3))) void LVoid;

__device__ __forceinline__ float gelu_exact(float x) {
    return 0.5f * x * (1.0f + erff(x * 0.70710678118654752f));
}
__device__ __forceinline__ unsigned short f2bf(float x) {
    return __hip_bfloat16_raw(__float2bfloat16(x)).x;
}

// ---------------------------------------------------------------------------
// bf16 MFMA GEMM, m97-style: C[M,N] = A[M,K](bf16) @ W[N,K](bf16)^T [+bias].
// BK=64, global_load_lds width=16 staging, XOR chunk-swizzled LDS (2-way max
// conflicts). 256 threads, 2x2 wave grid. TM in {32,64}; N%TN==0; K%64==0;
// A rows allocated up to ceil(M/TM)*TM. Store guarded by r<M.
// ---------------------------------------------------------------------------
template <int TM, int TN, int ACT_GELU, int OUT_BF16, int HAS_BIAS>
__global__ __launch_bounds__(256) void gemm_mfma(const unsigned short* __restrict__ A,
                                                 const unsigned short* __restrict__ W,
                                                 const float* __restrict__ bias,
                                                 void* __restrict__ Cv,
                                                 int M, int N, int K) {
    constexpr int WTM = TM / 2, WTN = TN / 2;
    constexpr int RM = WTM / 16, RN = WTN / 16;
    constexpr int AI = TM / 32;
    constexpr int BI = TN / 32;
    __shared__ __align__(16) unsigned short As[TM * 64];
    __shared__ __align__(16) unsigned short Bs[TN * 64];

    const int tid = threadIdx.x;
    const int wave = tid >> 6, lane = tid & 63;
    const int quad = lane >> 4, l16 = lane & 15;
    const int wm = wave >> 1, wn = wave & 1;
    const int bm = blockIdx.y * TM, bn = blockIdx.x * TN;

    const int sub = lane >> 3;
    const int cpr = (lane & 7) ^ sub;

    f32x4 acc[RM][RN];
#pragma unroll
    for (int i = 0; i < RM; i++)
#pragma unroll
        for (int j = 0; j < RN; j++) acc[i][j] = (f32x4){0.f, 0.f, 0.f, 0.f};

    for (int k0 = 0; k0 < K; k0 += 64) {
        __syncthreads();
#pragma unroll
        for (int i = 0; i < AI; i++) {
            int r0 = (wave * AI + i) * 8;
            const unsigned short* g = A + (size_t)(bm + r0 + sub) * K + k0 + cpr * 8;
            __builtin_amdgcn_global_load_lds((GVoid*)g, (LVoid*)&As[r0 * 64], 16, 0, 0);
        }
#pragma unroll
        for (int i = 0; i < BI; i++) {
            int r0 = (wave * BI + i) * 8;
            const unsigned short* g = W + (size_t)(bn + r0 + sub) * K + k0 + cpr * 8;
            __builtin_amdgcn_global_load_lds((GVoid*)g, (LVoid*)&Bs[r0 * 64], 16, 0, 0);
        }
        __syncthreads();

#pragma unroll
        for (int h = 0; h < 2; h++) {
            bf16x8 af[RM], bf[RN];
#pragma unroll
            for (int i = 0; i < RM; i++) {
                int r = wm * WTM + i * 16 + l16;
                int ch = (h * 4 + quad) ^ (r & 7);
                af[i] = *(const bf16x8*)&As[r * 64 + ch * 8];
            }
#pragma unroll
            for (int j = 0; j < RN; j++) {
                int r = wn * WTN + j * 16 + l16;
                int ch = (h * 4 + quad) ^ (r & 7);
                bf[j] = *(const bf16x8*)&Bs[r * 64 + ch * 8];
            }
#pragma unroll
            for (int i = 0; i < RM; i++)
#pragma unroll
                for (int j = 0; j < RN; j++)
                    acc[i][j] = __builtin_amdgcn_mfma_f32_16x16x32_bf16(af[i], bf[j], acc[i][j], 0, 0, 0);
        }
    }

#pragma unroll
    for (int i = 0; i < RM; i++) {
#pragma unroll
        for (int j = 0; j < RN; j++) {
            int c = bn + wn * WTN + j * 16 + l16;
            float bv = HAS_BIAS ? bias[c] : 0.f;
#pragma unroll
            for (int reg = 0; reg < 4; reg++) {
                int r = bm + wm * WTM + i * 16 + quad * 4 + reg;
                if (r < M) {
                    float v = acc[i][j][reg] + bv;
                    if (ACT_GELU) v = gelu_exact(v);
                    if (OUT_BF16)
                        ((unsigned short*)Cv)[(size_t)r * N + c] = f2bf(v);
                    else
                        ((float*)Cv)[(size_t)r * N + c] = v;
                }
            }
        }
    }
}

// fp32 GEMM (tiny q-proj only): C = A @ B^T + bias. 64x64 tile.
__global__ void gemm_nt(const float* __restrict__ A, const float* __restrict__ Bm,
                        const float* __restrict__ bias, float* __restrict__ C,
                        int M, int N, int K) {
    __shared__ float As[16][65];
    __shared__ float Bs[16][65];
    const int tid = threadIdx.x;
    const int bm = blockIdx.y * 64, bn = blockIdx.x * 64;
    const int tx = tid & 15, ty = tid >> 4;
    const int lrow = tid >> 2, lk = (tid & 3) << 2;
    float acc[4][4] = {{0.f}};
    const int arow = bm + lrow, brow = bn + lrow;
    for (int k0 = 0; k0 < K; k0 += 16) {
        float4 a4 = make_float4(0.f, 0.f, 0.f, 0.f);
        if (arow < M) a4 = *(const float4*)(A + (size_t)arow * K + k0 + lk);
        float4 b4 = *(const float4*)(Bm + (size_t)brow * K + k0 + lk);
        __syncthreads();
        As[lk + 0][lrow] = a4.x; As[lk + 1][lrow] = a4.y;
        As[lk + 2][lrow] = a4.z; As[lk + 3][lrow] = a4.w;
        Bs[lk + 0][lrow] = b4.x; Bs[lk + 1][lrow] = b4.y;
        Bs[lk + 2][lrow] = b4.z; Bs[lk + 3][lrow] = b4.w;
        __syncthreads();
#pragma unroll
        for (int kk = 0; kk < 16; kk++) {
            float av[4], bv[4];
#pragma unroll
            for (int i = 0; i < 4; i++) av[i] = As[kk][ty * 4 + i];
#pragma unroll
            for (int j = 0; j < 4; j++) bv[j] = Bs[kk][tx * 4 + j];
#pragma unroll
            for (int i = 0; i < 4; i++)
#pragma unroll
                for (int j = 0; j < 4; j++) acc[i][j] += av[i] * bv[j];
        }
    }
#pragma unroll
    for (int i = 0; i < 4; i++) {
        int r = bm + ty * 4 + i;
        if (r >= M) continue;
#pragma unroll
        for (int j = 0; j < 4; j++) {
            int c = bn + tx * 4 + j;
            C[(size_t)r * N + c] = acc[i][j] + bias[c];
        }
    }
}

// Multi-segment f32 -> bf16 convert (one launch for all weights).
struct CvtTable {
    const float* src[9];
    unsigned short* dst[9];
    int cum4[10];
};
__global__ void cvt_multi(CvtTable t, int total4) {
    int i = blockIdx.x * 256 + threadIdx.x;
    if (i >= total4) return;
    int k = 0;
#pragma unroll
    for (int j = 0; j < 8; j++) if (i >= t.cum4[j + 1]) k = j + 1;
    int o = i - t.cum4[k];
    float4 v = ((const float4*)t.src[k])[o];
    ushort4 u;
    u.x = f2bf(v.x); u.y = f2bf(v.y); u.z = f2bf(v.z); u.w = f2bf(v.w);
    ((ushort4*)t.dst[k])[o] = u;
}

// vwT[l][k][j] = vw[l][j][k], f32 -> bf16. grid (16,16,2), block (32,8).
__global__ void cvt_transpose512(const float* __restrict__ vw, unsigned short* __restrict__ vwT) {
    __shared__ float tile[32][33];
    int l = blockIdx.z;
    int j0 = blockIdx.y * 32, k0 = blockIdx.x * 32;
    const float* src = vw + (size_t)l * 512 * 512;
    for (int r = threadIdx.y; r < 32; r += 8)
        tile[r][threadIdx.x] = src[(size_t)(j0 + r) * 512 + k0 + threadIdx.x];
    __syncthreads();
    unsigned short* dst = vwT + (size_t)l * 512 * 512;
    for (int r = threadIdx.y; r < 32; r += 8)
        dst[(size_t)(k0 + r) * 512 + j0 + threadIdx.x] = f2bf(tile[threadIdx.x][r]);
}

// z<2: bfuse[z*512+n] = ow[z][n]·vb[z] + ob[z][n]; z==2: concat kv bias.
__global__ void prep_small(const float* __restrict__ ow, const float* __restrict__ vb,
                           const float* __restrict__ ob, const float* __restrict__ kb,
                           const float* __restrict__ vb2, float* __restrict__ bfuse,
                           float* __restrict__ kvb) {
    int n = blockIdx.x, z = blockIdx.y, lane = threadIdx.x;
    if (z == 2) {
        if (lane == 0) { kvb[n] = kb[n]; kvb[n + 512] = vb2[n]; }
        return;
    }
    const float* owr = ow + (size_t)z * 512 * 512 + (size_t)n * 512;
    const float* vbr = vb + (size_t)z * 512;
    float s = 0.f;
#pragma unroll
    for (int j = 0; j < 8; j++) s += owr[lane + 64 * j] * vbr[lane + 64 * j];
#pragma unroll
    for (int off = 32; off; off >>= 1) s += __shfl_xor(s, off, 64);
    if (lane == 0) bfuse[z * 512 + n] = s + ob[z * 512 + n];
}

// Row L2 norms of proj. grid = R_, block 64.
__global__ void rnorm_kernel(const float* __restrict__ proj, float* __restrict__ rn) {
    int r = blockIdx.x, lane = threadIdx.x;
    const float* p = proj + (size_t)r * D_;
    float s = 0.f;
#pragma unroll
    for (int j = 0; j < 8; j++) { float v = p[lane + 64 * j]; s += v * v; }
#pragma unroll
    for (int off = 32; off; off >>= 1) s += __shfl_xor(s, off, 64);
    if (lane == 0) rn[r] = sqrtf(s);
}

// Per-edge cosine sims -> stable top-8 -> mean agg (bf16) + states init (f32).
__global__ void sim_topk_agg(const int* __restrict__ eids, const int* __restrict__ nids,
                             const float* __restrict__ proj, const float* __restrict__ rn,
                             unsigned short* __restrict__ agg_bf, float* __restrict__ states) {
    int be = blockIdx.x, tid = threadIdx.x;
    __shared__ float ev[512];
    __shared__ float sims[32];
    __shared__ int nid_s[32];
    __shared__ int sel[8];

    int eid = eids[be];
    const float* ep = proj + (size_t)eid * D_;
    float e0 = ep[tid], e1 = ep[tid + 256];
    ev[tid] = e0; ev[tid + 256] = e1;
    states[(size_t)be * D_ + tid] = e0;
    states[(size_t)be * D_ + tid + 256] = e1;
    if (tid < 32) nid_s[tid] = nids[be * N_ + tid];
    __syncthreads();

    int wid = tid >> 6, lane = tid & 63;
    float en = fmaxf(rn[eid], 1e-12f);
    for (int n = wid; n < N_; n += 4) {
        int nid = nid_s[n];
        const float* np = proj + (size_t)nid * D_;
        float s = 0.f;
#pragma unroll
        for (int j = 0; j < 8; j++) s += np[lane + 64 * j] * ev[lane + 64 * j];
#pragma unroll
        for (int off = 32; off; off >>= 1) s += __shfl_xor(s, off, 64);
        if (lane == 0) sims[n] = s / (fmaxf(rn[nid], 1e-12f) * en);
    }
    __syncthreads();

    if (tid == 0) {
        unsigned used = 0;
        for (int k = 0; k < K_; k++) {
            float best = -3.402823466e38f; int bi = 0;
            for (int n = 0; n < N_; n++)
                if (!((used >> n) & 1u) && sims[n] > best) { best = sims[n]; bi = n; }
            used |= 1u << bi;
            sel[k] = nid_s[bi];
        }
    }
    __syncthreads();

    float a0 = 0.f, a1 = 0.f;
#pragma unroll
    for (int k = 0; k < K_; k++) {
        const float* sp = proj + (size_t)sel[k] * D_;
        a0 += sp[tid]; a1 += sp[tid + 256];
    }
    agg_bf[(size_t)be * D_ + tid] = f2bf(a0 * 0.125f);
    agg_bf[(size_t)be * D_ + tid + 256] = f2bf(a1 * 0.125f);
}

// out = LN(x + y)*g + b (optional *mask); y has row stride ystride.
__global__ void add_ln_kernel(const float* __restrict__ x, const float* __restrict__ y,
                              int ystride, const float* __restrict__ g,
                              const float* __restrict__ bb, const float* __restrict__ mask,
                              float* __restrict__ out, unsigned short* __restrict__ out_bf) {
    int t = blockIdx.x, tid = threadIdx.x;
    const float* xr = x + (size_t)t * D_;
    const float* yr = y + (size_t)t * ystride;
    float x0 = xr[tid] + yr[tid];
    float x1 = xr[tid + 256] + yr[tid + 256];
    __shared__ float red[8];
    float s = x0 + x1;
#pragma unroll
    for (int off = 32; off; off >>= 1) s += __shfl_xor(s, off, 64);
    int wid = tid >> 6;
    if ((tid & 63) == 0) red[wid] = s;
    __syncthreads();
    float mean = (red[0] + red[1] + red[2] + red[3]) * (1.f / 512.f);
    float d0 = x0 - mean, d1 = x1 - mean;
    float v = d0 * d0 + d1 * d1;
#pragma unroll
    for (int off = 32; off; off >>= 1) v += __shfl_xor(v, off, 64);
    if ((tid & 63) == 0) red[4 + wid] = v;
    __syncthreads();
    float var = (red[4] + red[5] + red[6] + red[7]) * (1.f / 512.f);
    float rs = rsqrtf(var + 1e-5f);
    float mv = mask ? mask[t] : 1.f;
    float o0 = (d0 * rs * g[tid] + bb[tid]) * mv;
    float o1 = (d1 * rs * g[tid + 256] + bb[tid + 256]) * mv;
    out[(size_t)t * D_ + tid] = o0;
    out[(size_t)t * D_ + tid + 256] = o1;
    out_bf[(size_t)t * D_ + tid] = f2bf(o0);
    out_bf[(size_t)t * D_ + tid + 256] = f2bf(o1);
}

// Cross-attention over combined kv [T,1024] (k cols 0-511, v cols 512-1023).
// grid = B_*M_*H_ (b in LOW 3 bits for XCD L2 locality), block 256
// (thread = edge). One (b,m,h) per block; same per-thread arithmetic order as
// the per-head loop version -> bit-identical output.
__global__ void mem_attn(const float* __restrict__ qb, const float* __restrict__ kv,
                         const float* __restrict__ mask, unsigned short* __restrict__ memb) {
    int idx = blockIdx.x;
    int b = idx & 7;            // low bits -> round-robin XCD gets stable b
    int h = (idx >> 3) & 7;
    int m = idx >> 6;
    int tid = threadIdx.x;
    __shared__ float qh[64];
    __shared__ float sc[256];
    __shared__ float red[8];
    __shared__ float oacc[4][64];

    float mk = mask[b * E_ + tid];
    if (tid < 64) qh[tid] = qb[m * D_ + h * DH_ + tid];
    __syncthreads();
    const float* kr = kv + ((size_t)(b * E_ + tid)) * 1024 + h * DH_;
    float s = 0.f;
#pragma unroll
    for (int d = 0; d < DH_; d += 4) {
        float4 k4 = *(const float4*)(kr + d);
        s += k4.x * qh[d] + k4.y * qh[d + 1] + k4.z * qh[d + 2] + k4.w * qh[d + 3];
    }
    s *= 0.125f;
    if (mk == 0.f) s = -3.402823466e38f;
    float mx = s;
#pragma unroll
    for (int off = 32; off; off >>= 1) mx = fmaxf(mx, __shfl_xor(mx, off, 64));
    if ((tid & 63) == 0) red[tid >> 6] = mx;
    __syncthreads();
    mx = fmaxf(fmaxf(red[0], red[1]), fmaxf(red[2], red[3]));
    float p = expf(s - mx);
    float sum = p;
#pragma unroll
    for (int off = 32; off; off >>= 1) sum += __shfl_xor(sum, off, 64);
    if ((tid & 63) == 0) red[4 + (tid >> 6)] = sum;
    __syncthreads();
    sum = red[4] + red[5] + red[6] + red[7];
    sc[tid] = p / sum;
    __syncthreads();
    int d = tid & 63, part = tid >> 6;
    const float* vcol = kv + ((size_t)(b * E_ + part * 64)) * 1024 + 512 + h * DH_ + d;
    float acc = 0.f;
#pragma unroll 8
    for (int e = 0; e < 64; e++) acc += sc[part * 64 + e] * vcol[(size_t)e * 1024];
    oacc[part][d] = acc;
    __syncthreads();
    if (part == 0)
        memb[((size_t)(b * M_ + m)) * D_ + h * DH_ + d] =
            f2bf(oacc[0][d] + oacc[1][d] + oacc[2][d] + oacc[3][d]);
}

// Zero bf16 mem rows of batches with zero edges. grid B_, block 256.
__global__ void mask_zero(const float* __restrict__ mask, unsigned short* __restrict__ mem2) {
    int b = blockIdx.x, tid = threadIdx.x;
    float s = mask[b * E_ + tid];
    __shared__ float red[4];
#pragma unroll
    for (int off = 32; off; off >>= 1) s += __shfl_xor(s, off, 64);
    if ((tid & 63) == 0) red[tid >> 6] = s;
    __syncthreads();
    if (red[0] + red[1] + red[2] + red[3] == 0.f) {
        for (int i = tid; i < M_ * D_; i += 256)
            mem2[(size_t)b * M_ * D_ + i] = 0;
    }
}

extern "C" void kernel_launch(void* const* d_in, const int* in_sizes, int n_in,
                              void* d_out, int out_size, void* d_ws, size_t ws_size,
                              hipStream_t stream) {
    const int*   edge_rel_ids     = (const int*)d_in[0];
    const int*   neighbor_rel_ids = (const int*)d_in[1];
    const float* edge_mask        = (const float*)d_in[2];
    const float* rel_emb          = (const float*)d_in[3];
    const float* rp_w             = (const float*)d_in[4];
    const float* rp_b             = (const float*)d_in[5];
    const float* ly_vw            = (const float*)d_in[6];
    const float* ly_vb            = (const float*)d_in[7];
    const float* ly_ow            = (const float*)d_in[8];
    const float* ly_ob            = (const float*)d_in[9];
    const float* ly_n1g           = (const float*)d_in[10];
    const float* ly_n1b           = (const float*)d_in[11];
    const float* ly_n2g           = (const float*)d_in[12];
    const float* ly_n2b           = (const float*)d_in[13];
    const float* ly_w1            = (const float*)d_in[14];
    const float* ly_b1            = (const float*)d_in[15];
    const float* ly_w2            = (const float*)d_in[16];
    const float* ly_b2            = (const float*)d_in[17];
    const float* mem_q            = (const float*)d_in[18];
    const float* t_qw             = (const float*)d_in[19];
    const float* t_qb             = (const float*)d_in[20];
    const float* t_kw             = (const float*)d_in[21];
    const float* t_kb             = (const float*)d_in[22];
    const float* t_vw             = (const float*)d_in[23];
    const float* t_vb             = (const float*)d_in[24];
    const float* t_ow             = (const float*)d_in[25];
    const float* t_ob             = (const float*)d_in[26];
    const float* proj_w           = (const float*)d_in[27];
    const float* proj_b           = (const float*)d_in[28];
    float* out = (float*)d_out;
    (void)ws_size; (void)in_sizes; (void)n_in; (void)out_size;

    char* ws = (char*)d_ws;
    size_t off = 0;
    auto allocf = [&](size_t n) { float* p = (float*)(ws + off); off += ((n * 4 + 255) & ~(size_t)255); return p; };
    auto allocb = [&](size_t n) { unsigned short* p = (unsigned short*)(ws + off); off += ((n * 2 + 255) & ~(size_t)255); return p; };

    const int T = B_ * E_;   // 2048

    float* proj    = allocf((size_t)R_ * D_);
    float* rn      = allocf(R_);
    float* states  = allocf((size_t)T * D_);
    float* tmpB    = allocf((size_t)T * D_);
    float* attnall = allocf((size_t)T * 2 * D_);
    float* qbuf    = allocf((size_t)M_ * D_);
    float* bfuse   = allocf(2 * D_);
    float* kvb     = allocf(2 * D_);
    float* kvbuf   = attnall;   // alias: attnall dead after layer stack

    unsigned short* rel_bf    = allocb((size_t)2048 * RD_);   // padded rows
    unsigned short* rpw_bf    = allocb((size_t)D_ * RD_);
    unsigned short* agg_bf    = allocb((size_t)T * D_);
    unsigned short* states_bf = allocb((size_t)T * D_);
    unsigned short* ff1_bf    = allocb((size_t)T * 4 * D_);
    unsigned short* vwT_bf    = allocb((size_t)L_ * D_ * D_);
    unsigned short* ow_bf     = allocb((size_t)L_ * D_ * D_);
    unsigned short* wfuse_bf  = allocb((size_t)L_ * D_ * D_);
    unsigned short* w1_bf     = allocb((size_t)L_ * 4 * D_ * D_);
    unsigned short* w2_bf     = allocb((size_t)L_ * 4 * D_ * D_);
    unsigned short* kvw_bf    = allocb((size_t)2 * D_ * D_);
    unsigned short* tow_bf    = allocb((size_t)D_ * D_);
    unsigned short* pw_bf     = allocb((size_t)HL_ * D_);
    unsigned short* memb_bf   = allocb((size_t)B_ * M_ * D_);
    unsigned short* mem2_bf   = allocb((size_t)B_ * M_ * D_);

    // 0a. straight f32->bf16 conversions in one kernel
    CvtTable t;
    int sizes[9] = { R_ * RD_, D_ * RD_, L_ * D_ * D_, L_ * 4 * D_ * D_,
                     L_ * 4 * D_ * D_, D_ * D_, D_ * D_, D_ * D_, HL_ * D_ };
    const float* srcs[9] = { rel_emb, rp_w, ly_ow, ly_w1, ly_w2, t_kw, t_vw, t_ow, proj_w };
    unsigned short* dsts[9] = { rel_bf, rpw_bf, ow_bf, w1_bf, w2_bf,
                                kvw_bf, kvw_bf + (size_t)D_ * D_, tow_bf, pw_bf };
    int cum = 0;
    for (int i = 0; i < 9; i++) {
        t.src[i] = srcs[i]; t.dst[i] = dsts[i];
        t.cum4[i] = cum; cum += sizes[i] / 4;
    }
    t.cum4[9] = cum;
    cvt_multi<<<(cum + 255) / 256, 256, 0, stream>>>(t, cum);
    // 0b. vw transposed convert
    cvt_transpose512<<<dim3(16, 16, 2), dim3(32, 8), 0, stream>>>(ly_vw, vwT_bf);
    // 0c. fused biases
    prep_small<<<dim3(512, 3), 64, 0, stream>>>(ly_ow, ly_vb, ly_ob, t_kb, t_vb, bfuse, kvb);

    // 1. proj = rel_emb @ rp_w^T + rp_b  (TM=32 -> 512 blocks)
    gemm_mfma<32, 64, 0, 0, 1><<<dim3(D_ / 64, 64), 256, 0, stream>>>(
        rel_bf, rpw_bf, rp_b, proj, R_, D_, RD_);
    // 2. norms
    rnorm_kernel<<<R_, 64, 0, stream>>>(proj, rn);
    // 3. sims + top-k + aggregate + states init
    sim_topk_agg<<<T, 256, 0, stream>>>(edge_rel_ids, neighbor_rel_ids, proj, rn,
                                        agg_bf, states);

    // 4a. Wfuse_l = ow_l @ vw_l (bf16 out)
    for (int l = 0; l < L_; l++)
        gemm_mfma<32, 64, 0, 1, 0><<<dim3(8, 16), 256, 0, stream>>>(
            ow_bf + (size_t)l * D_ * D_, vwT_bf + (size_t)l * D_ * D_, nullptr,
            wfuse_bf + (size_t)l * D_ * D_, D_, D_, D_);
    // 4b. attn (both layers) = agg @ Wfuse^T + bfuse  [2048,1024], 512 blocks
    gemm_mfma<64, 64, 0, 0, 1><<<dim3(2 * D_ / 64, T / 64), 256, 0, stream>>>(
        agg_bf, wfuse_bf, bfuse, attnall, T, 2 * D_, D_);

    // 4c. layer stack
    for (int l = 0; l < L_; l++) {
        add_ln_kernel<<<T, 256, 0, stream>>>(states, attnall + (size_t)l * D_, 2 * D_,
                                             ly_n1g + l * D_, ly_n1b + l * D_, nullptr,
                                             states, states_bf);
        gemm_mfma<64, 64, 1, 1, 1><<<dim3(4 * D_ / 64, T / 64), 256, 0, stream>>>(
            states_bf, w1_bf + (size_t)l * 4 * D_ * D_, ly_b1 + l * 4 * D_,
            ff1_bf, T, 4 * D_, D_);
        gemm_mfma<32, 64, 0, 0, 1><<<dim3(D_ / 64, T / 32), 256, 0, stream>>>(
            ff1_bf, w2_bf + (size_t)l * 4 * D_ * D_, ly_b2 + l * D_,
            tmpB, T, D_, 4 * D_);
        add_ln_kernel<<<T, 256, 0, stream>>>(states, tmpB, D_,
                                             ly_n2g + l * D_, ly_n2b + l * D_, edge_mask,
                                             states, states_bf);
    }

    // 5. combined k|v projection -> kvbuf [2048,1024], 512 blocks
    gemm_mfma<64, 64, 0, 0, 1><<<dim3(2 * D_ / 64, T / 64), 256, 0, stream>>>(
        states_bf, kvw_bf, kvb, kvbuf, T, 2 * D_, D_);
    // q projection (tiny, exact fp32)
    gemm_nt<<<dim3(D_ / 64, 1), 256, 0, stream>>>(mem_q, t_qw, t_qb, qbuf, M_, D_, D_);

    // 6. memory cross-attention -> memb (bf16), 2048 blocks (b,m,h)
    mem_attn<<<B_ * M_ * H_, 256, 0, stream>>>(qbuf, kvbuf, edge_mask, memb_bf);

    // 7. out-proj of attention + no-edge zeroing
    gemm_mfma<32, 64, 0, 1, 1><<<dim3(D_ / 64, 8), 256, 0, stream>>>(
        memb_bf, tow_bf, t_ob, mem2_bf, B_ * M_, D_, D_);
    mask_zero<<<B_, 256, 0, stream>>>(edge_mask, mem2_bf);

    // 8. final LLM projection [256,4096,512] -> TM=32, 512 blocks
    gemm_mfma<32, 64, 0, 0, 1><<<dim3(HL_ / 64, 8), 256, 0, stream>>>(
        mem2_bf, pw_bf, proj_b, out, B_ * M_, HL_, D_);
}

// Round 8
// 322.059 us; speedup vs baseline: 3.3244x; 1.1237x over previous
//
#include <hip/hip_runtime.h>
#include <hip/hip_bf16.h>
#include <math.h>

#define B_   8
#define E_   256
#define N_   32
#define D_   512
#define RD_  768
#define R_   2000
#define L_   2
#define K_   8
#define M_   32
#define H_   8
#define DH_  64
#define HL_  4096

typedef float f32x4 __attribute__((ext_vector_type(4)));
typedef __bf16 bf16x8 __attribute__((ext_vector_type(8)));
typedef const __attribute__((address_space(1))) void GVoid;
typedef __attribute__((address_space(3))) void LVoid;

__device__ __forceinline__ float gelu_exact(float x) {
    return 0.5f * x * (1.0f + erff(x * 0.70710678118654752f));
}
__device__ __forceinline__ unsigned short f2bf(float x) {
    return __hip_bfloat16_raw(__float2bfloat16(x)).x;
}

// ---------------------------------------------------------------------------
// bf16 MFMA GEMM, m97-style: C[M,N] = A[M,K](bf16) @ W[N,K](bf16)^T [+bias].
// BK=64, global_load_lds width=16 staging, XOR chunk-swizzled LDS (2-way max
// conflicts). 256 threads, 2x2 wave grid. TM in {32,64}; N%TN==0; K%64==0;
// A rows allocated up to ceil(M/TM)*TM. Store guarded by r<M.
// Optional: batch via blockIdx.z with element strides sA/sW/sC.
// Optional FLAGS: multiply output by rowflag[r>>5] (per-32-row scale).
// ---------------------------------------------------------------------------
template <int TM, int TN, int ACT_GELU, int OUT_BF16, int HAS_BIAS, int FLAGS>
__global__ __launch_bounds__(256) void gemm_mfma(const unsigned short* __restrict__ A,
                                                 const unsigned short* __restrict__ W,
                                                 const float* __restrict__ bias,
                                                 void* __restrict__ Cv,
                                                 int M, int N, int K,
                                                 size_t sA, size_t sW, size_t sC,
                                                 const float* __restrict__ rowflag) {
    constexpr int WTM = TM / 2, WTN = TN / 2;
    constexpr int RM = WTM / 16, RN = WTN / 16;
    constexpr int AI = TM / 32;
    constexpr int BI = TN / 32;
    __shared__ __align__(16) unsigned short As[TM * 64];
    __shared__ __align__(16) unsigned short Bs[TN * 64];

    const size_t z = blockIdx.z;
    A += z * sA; W += z * sW;

    const int tid = threadIdx.x;
    const int wave = tid >> 6, lane = tid & 63;
    const int quad = lane >> 4, l16 = lane & 15;
    const int wm = wave >> 1, wn = wave & 1;
    const int bm = blockIdx.y * TM, bn = blockIdx.x * TN;

    const int sub = lane >> 3;
    const int cpr = (lane & 7) ^ sub;

    f32x4 acc[RM][RN];
#pragma unroll
    for (int i = 0; i < RM; i++)
#pragma unroll
        for (int j = 0; j < RN; j++) acc[i][j] = (f32x4){0.f, 0.f, 0.f, 0.f};

    for (int k0 = 0; k0 < K; k0 += 64) {
        __syncthreads();
#pragma unroll
        for (int i = 0; i < AI; i++) {
            int r0 = (wave * AI + i) * 8;
            const unsigned short* g = A + (size_t)(bm + r0 + sub) * K + k0 + cpr * 8;
            __builtin_amdgcn_global_load_lds((GVoid*)g, (LVoid*)&As[r0 * 64], 16, 0, 0);
        }
#pragma unroll
        for (int i = 0; i < BI; i++) {
            int r0 = (wave * BI + i) * 8;
            const unsigned short* g = W + (size_t)(bn + r0 + sub) * K + k0 + cpr * 8;
            __builtin_amdgcn_global_load_lds((GVoid*)g, (LVoid*)&Bs[r0 * 64], 16, 0, 0);
        }
        __syncthreads();

#pragma unroll
        for (int h = 0; h < 2; h++) {
            bf16x8 af[RM], bf[RN];
#pragma unroll
            for (int i = 0; i < RM; i++) {
                int r = wm * WTM + i * 16 + l16;
                int ch = (h * 4 + quad) ^ (r & 7);
                af[i] = *(const bf16x8*)&As[r * 64 + ch * 8];
            }
#pragma unroll
            for (int j = 0; j < RN; j++) {
                int r = wn * WTN + j * 16 + l16;
                int ch = (h * 4 + quad) ^ (r & 7);
                bf[j] = *(const bf16x8*)&Bs[r * 64 + ch * 8];
            }
#pragma unroll
            for (int i = 0; i < RM; i++)
#pragma unroll
                for (int j = 0; j < RN; j++)
                    acc[i][j] = __builtin_amdgcn_mfma_f32_16x16x32_bf16(af[i], bf[j], acc[i][j], 0, 0, 0);
        }
    }

#pragma unroll
    for (int i = 0; i < RM; i++) {
#pragma unroll
        for (int j = 0; j < RN; j++) {
            int c = bn + wn * WTN + j * 16 + l16;
            float bv = HAS_BIAS ? bias[c] : 0.f;
#pragma unroll
            for (int reg = 0; reg < 4; reg++) {
                int r = bm + wm * WTM + i * 16 + quad * 4 + reg;
                if (r < M) {
                    float v = acc[i][j][reg] + bv;
                    if (ACT_GELU) v = gelu_exact(v);
                    if (FLAGS) v *= rowflag[r >> 5];
                    if (OUT_BF16)
                        ((unsigned short*)(Cv))[z * sC + (size_t)r * N + c] = f2bf(v);
                    else
                        ((float*)(Cv))[z * sC + (size_t)r * N + c] = v;
                }
            }
        }
    }
}

// ---------------------------------------------------------------------------
// prep_all: one launch for all input-only preprocessing.
// Sections by blockIdx.x:
//  S0 [nb_cvt):  straight f32->bf16 conversions (9 segments)
//  S1 [nb_tr):   vw transpose+convert (512 blocks: l*256 + 16x16 tile id)
//  S2 [nb_bf):   bfuse = ow·vb + ob  (1024 wave-dots, 4/block)
//  S3 [1):       kvb concat + per-batch edge flags
//  S4 [rest):    q-proj: 16384 wave-dots (4/block)
// ---------------------------------------------------------------------------
struct PrepArgs {
    const float* src[9];
    unsigned short* dst[9];
    int cum4[10];
    int nb_cvt, nb_tr, nb_bf, total4;
    const float* ly_vw; unsigned short* vwT;
    const float* ly_ow; const float* ly_vb; const float* ly_ob; float* bfuse;
    const float* t_kb; const float* t_vb; float* kvb;
    const float* edge_mask; float* flags;
    const float* mem_q; const float* t_qw; const float* t_qb; float* qbuf;
};

__global__ __launch_bounds__(256) void prep_all(PrepArgs a) {
    int bx = blockIdx.x, tid = threadIdx.x;
    if (bx < a.nb_cvt) {                       // S0: cvt
        int i = bx * 256 + tid;
        if (i < a.total4) {
            int k = 0;
#pragma unroll
            for (int j = 0; j < 8; j++) if (i >= a.cum4[j + 1]) k = j + 1;
            int o = i - a.cum4[k];
            float4 v = ((const float4*)a.src[k])[o];
            ushort4 u;
            u.x = f2bf(v.x); u.y = f2bf(v.y); u.z = f2bf(v.z); u.w = f2bf(v.w);
            ((ushort4*)a.dst[k])[o] = u;
        }
        return;
    }
    bx -= a.nb_cvt;
    if (bx < a.nb_tr) {                        // S1: transpose vw
        __shared__ float tile[32][33];
        int l = bx >> 8, t16 = bx & 255;
        int j0 = (t16 >> 4) * 32, k0 = (t16 & 15) * 32;
        int tx = tid & 31, ty = tid >> 5;      // 32x8
        const float* src = a.ly_vw + (size_t)l * 512 * 512;
        for (int r = ty; r < 32; r += 8)
            tile[r][tx] = src[(size_t)(j0 + r) * 512 + k0 + tx];
        __syncthreads();
        unsigned short* dst = a.vwT + (size_t)l * 512 * 512;
        for (int r = ty; r < 32; r += 8)
            dst[(size_t)(k0 + r) * 512 + j0 + tx] = f2bf(tile[tx][r]);
        return;
    }
    bx -= a.nb_tr;
    if (bx < a.nb_bf) {                        // S2: bfuse wave-dots
        int wid = bx * 4 + (tid >> 6);         // 0..1023
        int z = wid >> 9, n = wid & 511, lane = tid & 63;
        const float* owr = a.ly_ow + (size_t)z * 512 * 512 + (size_t)n * 512;
        const float* vbr = a.ly_vb + (size_t)z * 512;
        float s = 0.f;
#pragma unroll
        for (int j = 0; j < 8; j++) s += owr[lane + 64 * j] * vbr[lane + 64 * j];
#pragma unroll
        for (int off = 32; off; off >>= 1) s += __shfl_xor(s, off, 64);
        if (lane == 0) a.bfuse[z * 512 + n] = s + a.ly_ob[z * 512 + n];
        return;
    }
    bx -= a.nb_bf;
    if (bx < 1) {                              // S3: kvb + flags
        for (int n = tid; n < 512; n += 256) {
            a.kvb[n] = a.t_kb[n];
            a.kvb[n + 512] = a.t_vb[n];
        }
        __shared__ float red[4];
        for (int b = 0; b < B_; b++) {
            float s = a.edge_mask[b * E_ + tid];
#pragma unroll
            for (int off = 32; off; off >>= 1) s += __shfl_xor(s, off, 64);
            if ((tid & 63) == 0) red[tid >> 6] = s;
            __syncthreads();
            if (tid == 0)
                a.flags[b] = (red[0] + red[1] + red[2] + red[3] == 0.f) ? 0.f : 1.f;
            __syncthreads();
        }
        return;
    }
    bx -= 1;
    {                                          // S4: q-proj wave-dots
        int wid = bx * 4 + (tid >> 6);         // 0..16383
        int m = wid >> 9, n = wid & 511, lane = tid & 63;
        const float* ar = a.mem_q + (size_t)m * 512;
        const float* br = a.t_qw + (size_t)n * 512;
        float s = 0.f;
#pragma unroll
        for (int j = 0; j < 8; j++) s += ar[lane + 64 * j] * br[lane + 64 * j];
#pragma unroll
        for (int off = 32; off; off >>= 1) s += __shfl_xor(s, off, 64);
        if (lane == 0) a.qbuf[(size_t)m * 512 + n] = s + a.t_qb[n];
    }
}

// Per-edge cosine sims (norms inline, bit-identical order to the old rnorm) ->
// stable top-8 -> mean agg (bf16) + states init (f32). grid = B_*E_, block 256.
__global__ void sim_topk_agg(const int* __restrict__ eids, const int* __restrict__ nids,
                             const float* __restrict__ proj,
                             unsigned short* __restrict__ agg_bf, float* __restrict__ states) {
    int be = blockIdx.x, tid = threadIdx.x;
    __shared__ float ev[512];
    __shared__ float sims[32];
    __shared__ int nid_s[32];
    __shared__ int sel[8];

    int eid = eids[be];
    const float* ep = proj + (size_t)eid * D_;
    float e0 = ep[tid], e1 = ep[tid + 256];
    ev[tid] = e0; ev[tid + 256] = e1;
    states[(size_t)be * D_ + tid] = e0;
    states[(size_t)be * D_ + tid + 256] = e1;
    if (tid < 32) nid_s[tid] = nids[be * N_ + tid];
    __syncthreads();

    int wid = tid >> 6, lane = tid & 63;
    // edge norm (each wave computes redundantly; same order as old rnorm)
    float se = 0.f;
#pragma unroll
    for (int j = 0; j < 8; j++) { float v = ev[lane + 64 * j]; se += v * v; }
#pragma unroll
    for (int off = 32; off; off >>= 1) se += __shfl_xor(se, off, 64);
    float en = fmaxf(sqrtf(se), 1e-12f);

    for (int n = wid; n < N_; n += 4) {
        int nid = nid_s[n];
        const float* np = proj + (size_t)nid * D_;
        float s = 0.f, s2 = 0.f;
#pragma unroll
        for (int j = 0; j < 8; j++) {
            float v = np[lane + 64 * j];
            s += v * ev[lane + 64 * j];
            s2 += v * v;
        }
#pragma unroll
        for (int off = 32; off; off >>= 1) {
            s += __shfl_xor(s, off, 64);
            s2 += __shfl_xor(s2, off, 64);
        }
        if (lane == 0) sims[n] = s / (fmaxf(sqrtf(s2), 1e-12f) * en);
    }
    __syncthreads();

    if (tid == 0) {
        unsigned used = 0;
        for (int k = 0; k < K_; k++) {
            float best = -3.402823466e38f; int bi = 0;
            for (int n = 0; n < N_; n++)
                if (!((used >> n) & 1u) && sims[n] > best) { best = sims[n]; bi = n; }
            used |= 1u << bi;
            sel[k] = nid_s[bi];
        }
    }
    __syncthreads();

    float a0 = 0.f, a1 = 0.f;
#pragma unroll
    for (int k = 0; k < K_; k++) {
        const float* sp = proj + (size_t)sel[k] * D_;
        a0 += sp[tid]; a1 += sp[tid + 256];
    }
    agg_bf[(size_t)be * D_ + tid] = f2bf(a0 * 0.125f);
    agg_bf[(size_t)be * D_ + tid + 256] = f2bf(a1 * 0.125f);
}

// out = LN(x + y)*g + b (optional *mask); y has row stride ystride.
__global__ void add_ln_kernel(const float* __restrict__ x, const float* __restrict__ y,
                              int ystride, const float* __restrict__ g,
                              const float* __restrict__ bb, const float* __restrict__ mask,
                              float* __restrict__ out, unsigned short* __restrict__ out_bf) {
    int t = blockIdx.x, tid = threadIdx.x;
    const float* xr = x + (size_t)t * D_;
    const float* yr = y + (size_t)t * ystride;
    float x0 = xr[tid] + yr[tid];
    float x1 = xr[tid + 256] + yr[tid + 256];
    __shared__ float red[8];
    float s = x0 + x1;
#pragma unroll
    for (int off = 32; off; off >>= 1) s += __shfl_xor(s, off, 64);
    int wid = tid >> 6;
    if ((tid & 63) == 0) red[wid] = s;
    __syncthreads();
    float mean = (red[0] + red[1] + red[2] + red[3]) * (1.f / 512.f);
    float d0 = x0 - mean, d1 = x1 - mean;
    float v = d0 * d0 + d1 * d1;
#pragma unroll
    for (int off = 32; off; off >>= 1) v += __shfl_xor(v, off, 64);
    if ((tid & 63) == 0) red[4 + wid] = v;
    __syncthreads();
    float var = (red[4] + red[5] + red[6] + red[7]) * (1.f / 512.f);
    float rs = rsqrtf(var + 1e-5f);
    float mv = mask ? mask[t] : 1.f;
    float o0 = (d0 * rs * g[tid] + bb[tid]) * mv;
    float o1 = (d1 * rs * g[tid + 256] + bb[tid + 256]) * mv;
    out[(size_t)t * D_ + tid] = o0;
    out[(size_t)t * D_ + tid + 256] = o1;
    out_bf[(size_t)t * D_ + tid] = f2bf(o0);
    out_bf[(size_t)t * D_ + tid + 256] = f2bf(o1);
}

// Cross-attention over combined kv [T,1024]. grid = B_*M_*H_ (b in low bits),
// block 256 (thread = edge). One (b,m,h) per block.
__global__ void mem_attn(const float* __restrict__ qb, const float* __restrict__ kv,
                         const float* __restrict__ mask, unsigned short* __restrict__ memb) {
    int idx = blockIdx.x;
    int b = idx & 7;
    int h = (idx >> 3) & 7;
    int m = idx >> 6;
    int tid = threadIdx.x;
    __shared__ float qh[64];
    __shared__ float sc[256];
    __shared__ float red[8];
    __shared__ float oacc[4][64];

    float mk = mask[b * E_ + tid];
    if (tid < 64) qh[tid] = qb[m * D_ + h * DH_ + tid];
    __syncthreads();
    const float* kr = kv + ((size_t)(b * E_ + tid)) * 1024 + h * DH_;
    float s = 0.f;
#pragma unroll
    for (int d = 0; d < DH_; d += 4) {
        float4 k4 = *(const float4*)(kr + d);
        s += k4.x * qh[d] + k4.y * qh[d + 1] + k4.z * qh[d + 2] + k4.w * qh[d + 3];
    }
    s *= 0.125f;
    if (mk == 0.f) s = -3.402823466e38f;
    float mx = s;
#pragma unroll
    for (int off = 32; off; off >>= 1) mx = fmaxf(mx, __shfl_xor(mx, off, 64));
    if ((tid & 63) == 0) red[tid >> 6] = mx;
    __syncthreads();
    mx = fmaxf(fmaxf(red[0], red[1]), fmaxf(red[2], red[3]));
    float p = expf(s - mx);
    float sum = p;
#pragma unroll
    for (int off = 32; off; off >>= 1) sum += __shfl_xor(sum, off, 64);
    if ((tid & 63) == 0) red[4 + (tid >> 6)] = sum;
    __syncthreads();
    sum = red[4] + red[5] + red[6] + red[7];
    sc[tid] = p / sum;
    __syncthreads();
    int d = tid & 63, part = tid >> 6;
    const float* vcol = kv + ((size_t)(b * E_ + part * 64)) * 1024 + 512 + h * DH_ + d;
    float acc = 0.f;
#pragma unroll 8
    for (int e = 0; e < 64; e++) acc += sc[part * 64 + e] * vcol[(size_t)e * 1024];
    oacc[part][d] = acc;
    __syncthreads();
    if (part == 0)
        memb[((size_t)(b * M_ + m)) * D_ + h * DH_ + d] =
            f2bf(oacc[0][d] + oacc[1][d] + oacc[2][d] + oacc[3][d]);
}

extern "C" void kernel_launch(void* const* d_in, const int* in_sizes, int n_in,
                              void* d_out, int out_size, void* d_ws, size_t ws_size,
                              hipStream_t stream) {
    const int*   edge_rel_ids     = (const int*)d_in[0];
    const int*   neighbor_rel_ids = (const int*)d_in[1];
    const float* edge_mask        = (const float*)d_in[2];
    const float* rel_emb          = (const float*)d_in[3];
    const float* rp_w             = (const float*)d_in[4];
    const float* rp_b             = (const float*)d_in[5];
    const float* ly_vw            = (const float*)d_in[6];
    const float* ly_vb            = (const float*)d_in[7];
    const float* ly_ow            = (const float*)d_in[8];
    const float* ly_ob            = (const float*)d_in[9];
    const float* ly_n1g           = (const float*)d_in[10];
    const float* ly_n1b           = (const float*)d_in[11];
    const float* ly_n2g           = (const float*)d_in[12];
    const float* ly_n2b           = (const float*)d_in[13];
    const float* ly_w1            = (const float*)d_in[14];
    const float* ly_b1            = (const float*)d_in[15];
    const float* ly_w2            = (const float*)d_in[16];
    const float* ly_b2            = (const float*)d_in[17];
    const float* mem_q            = (const float*)d_in[18];
    const float* t_qw             = (const float*)d_in[19];
    const float* t_qb             = (const float*)d_in[20];
    const float* t_kw             = (const float*)d_in[21];
    const float* t_kb             = (const float*)d_in[22];
    const float* t_vw             = (const float*)d_in[23];
    const float* t_vb             = (const float*)d_in[24];
    const float* t_ow             = (const float*)d_in[25];
    const float* t_ob             = (const float*)d_in[26];
    const float* proj_w           = (const float*)d_in[27];
    const float* proj_b           = (const float*)d_in[28];
    float* out = (float*)d_out;
    (void)ws_size; (void)in_sizes; (void)n_in; (void)out_size;

    char* ws = (char*)d_ws;
    size_t off = 0;
    auto allocf = [&](size_t n) { float* p = (float*)(ws + off); off += ((n * 4 + 255) & ~(size_t)255); return p; };
    auto allocb = [&](size_t n) { unsigned short* p = (unsigned short*)(ws + off); off += ((n * 2 + 255) & ~(size_t)255); return p; };

    const int T = B_ * E_;   // 2048

    float* proj    = allocf((size_t)R_ * D_);
    float* states  = allocf((size_t)T * D_);
    float* tmpB    = allocf((size_t)T * D_);
    float* attnall = allocf((size_t)T * 2 * D_);
    float* qbuf    = allocf((size_t)M_ * D_);
    float* bfuse   = allocf(2 * D_);
    float* kvb     = allocf(2 * D_);
    float* flags   = allocf(B_);
    float* kvbuf   = attnall;   // alias: attnall dead after layer stack

    unsigned short* rel_bf    = allocb((size_t)2048 * RD_);   // padded rows
    unsigned short* rpw_bf    = allocb((size_t)D_ * RD_);
    unsigned short* agg_bf    = allocb((size_t)T * D_);
    unsigned short* states_bf = allocb((size_t)T * D_);
    unsigned short* ff1_bf    = allocb((size_t)T * 4 * D_);
    unsigned short* vwT_bf    = allocb((size_t)L_ * D_ * D_);
    unsigned short* ow_bf     = allocb((size_t)L_ * D_ * D_);
    unsigned short* wfuse_bf  = allocb((size_t)L_ * D_ * D_);
    unsigned short* w1_bf     = allocb((size_t)L_ * 4 * D_ * D_);
    unsigned short* w2_bf     = allocb((size_t)L_ * 4 * D_ * D_);
    unsigned short* kvw_bf    = allocb((size_t)2 * D_ * D_);
    unsigned short* tow_bf    = allocb((size_t)D_ * D_);
    unsigned short* pw_bf     = allocb((size_t)HL_ * D_);
    unsigned short* memb_bf   = allocb((size_t)B_ * M_ * D_);
    unsigned short* mem2_bf   = allocb((size_t)B_ * M_ * D_);

    // ---- 0. one prep launch: cvt + transpose + bfuse/kvb/flags + q-proj ----
    PrepArgs a;
    int sizes[9] = { R_ * RD_, D_ * RD_, L_ * D_ * D_, L_ * 4 * D_ * D_,
                     L_ * 4 * D_ * D_, D_ * D_, D_ * D_, D_ * D_, HL_ * D_ };
    const float* srcs[9] = { rel_emb, rp_w, ly_ow, ly_w1, ly_w2, t_kw, t_vw, t_ow, proj_w };
    unsigned short* dsts[9] = { rel_bf, rpw_bf, ow_bf, w1_bf, w2_bf,
                                kvw_bf, kvw_bf + (size_t)D_ * D_, tow_bf, pw_bf };
    int cum = 0;
    for (int i = 0; i < 9; i++) {
        a.src[i] = srcs[i]; a.dst[i] = dsts[i];
        a.cum4[i] = cum; cum += sizes[i] / 4;
    }
    a.cum4[9] = cum;
    a.total4 = cum;
    a.nb_cvt = (cum + 255) / 256;
    a.nb_tr = 512;
    a.nb_bf = 256;
    a.ly_vw = ly_vw; a.vwT = vwT_bf;
    a.ly_ow = ly_ow; a.ly_vb = ly_vb; a.ly_ob = ly_ob; a.bfuse = bfuse;
    a.t_kb = t_kb; a.t_vb = t_vb; a.kvb = kvb;
    a.edge_mask = edge_mask; a.flags = flags;
    a.mem_q = mem_q; a.t_qw = t_qw; a.t_qb = t_qb; a.qbuf = qbuf;
    int nblk = a.nb_cvt + a.nb_tr + a.nb_bf + 1 + 4096;
    prep_all<<<nblk, 256, 0, stream>>>(a);

    // ---- 1. proj = rel_emb @ rp_w^T + rp_b ----
    gemm_mfma<32, 64, 0, 0, 1, 0><<<dim3(D_ / 64, 64), 256, 0, stream>>>(
        rel_bf, rpw_bf, rp_b, proj, R_, D_, RD_, 0, 0, 0, nullptr);
    // ---- 2. sims (norms inline) + top-k + aggregate + states init ----
    sim_topk_agg<<<T, 256, 0, stream>>>(edge_rel_ids, neighbor_rel_ids, proj,
                                        agg_bf, states);

    // ---- 3. Wfuse_l = ow_l @ vw_l, batched over l via blockIdx.z ----
    gemm_mfma<32, 64, 0, 1, 0, 0><<<dim3(8, 16, 2), 256, 0, stream>>>(
        ow_bf, vwT_bf, nullptr, wfuse_bf, D_, D_, D_,
        (size_t)D_ * D_, (size_t)D_ * D_, (size_t)D_ * D_, nullptr);
    // ---- 4. attn (both layers) = agg @ Wfuse^T + bfuse  [2048,1024] ----
    gemm_mfma<64, 64, 0, 0, 1, 0><<<dim3(2 * D_ / 64, T / 64), 256, 0, stream>>>(
        agg_bf, wfuse_bf, bfuse, attnall, T, 2 * D_, D_, 0, 0, 0, nullptr);

    // ---- 5. layer stack ----
    for (int l = 0; l < L_; l++) {
        add_ln_kernel<<<T, 256, 0, stream>>>(states, attnall + (size_t)l * D_, 2 * D_,
                                             ly_n1g + l * D_, ly_n1b + l * D_, nullptr,
                                             states, states_bf);
        gemm_mfma<64, 64, 1, 1, 1, 0><<<dim3(4 * D_ / 64, T / 64), 256, 0, stream>>>(
            states_bf, w1_bf + (size_t)l * 4 * D_ * D_, ly_b1 + l * 4 * D_,
            ff1_bf, T, 4 * D_, D_, 0, 0, 0, nullptr);
        gemm_mfma<32, 64, 0, 0, 1, 0><<<dim3(D_ / 64, T / 32), 256, 0, stream>>>(
            ff1_bf, w2_bf + (size_t)l * 4 * D_ * D_, ly_b2 + l * D_,
            tmpB, T, D_, 4 * D_, 0, 0, 0, nullptr);
        add_ln_kernel<<<T, 256, 0, stream>>>(states, tmpB, D_,
                                             ly_n2g + l * D_, ly_n2b + l * D_, edge_mask,
                                             states, states_bf);
    }

    // ---- 6. combined k|v projection -> kvbuf [2048,1024] ----
    gemm_mfma<64, 64, 0, 0, 1, 0><<<dim3(2 * D_ / 64, T / 64), 256, 0, stream>>>(
        states_bf, kvw_bf, kvb, kvbuf, T, 2 * D_, D_, 0, 0, 0, nullptr);

    // ---- 7. memory cross-attention -> memb (bf16) ----
    mem_attn<<<B_ * M_ * H_, 256, 0, stream>>>(qbuf, kvbuf, edge_mask, memb_bf);

    // ---- 8. out-proj of attention, no-edge zeroing fused via flags ----
    gemm_mfma<32, 64, 0, 1, 1, 1><<<dim3(D_ / 64, 8), 256, 0, stream>>>(
        memb_bf, tow_bf, t_ob, mem2_bf, B_ * M_, D_, D_, 0, 0, 0, flags);

    // ---- 9. final LLM projection [256,4096,512] ----
    gemm_mfma<32, 64, 0, 0, 1, 0><<<dim3(HL_ / 64, 8), 256, 0, stream>>>(
        mem2_bf, pw_bf, proj_b, out, B_ * M_, HL_, D_, 0, 0, 0, nullptr);
}